// Round 6
// baseline (1127.536 us; speedup 1.0000x reference)
//
#include <hip/hip_runtime.h>
#include <hip/hip_bf16.h>

#define NN 10000     // nodes
#define NE 100000    // edges
#define DD 64        // node_out_feats
#define EH_ 128      // edge_hidden_feats
#define NI_ 74       // node_in_feats
#define EI_ 12       // edge_in_feats
#define NSTEPS 6
#define PADN 10240

typedef short bf16x8 __attribute__((ext_vector_type(8)));
typedef float f32x4 __attribute__((ext_vector_type(4)));

static __device__ __forceinline__ unsigned short f2b(float f) {
    unsigned int u = __float_as_uint(f);
    u += 0x7fffu + ((u >> 16) & 1u);
    return (unsigned short)(u >> 16);
}

__global__ void k_zero(float* p, int n) {
    int i = blockIdx.x * blockDim.x + threadIdx.x;
    if (i < n) p[i] = 0.f;
}

// node_feats = relu(x @ W_proj^T + b_proj); hidden = node_feats. One wave per node.
__global__ void k_proj(const float* __restrict__ x, const float* __restrict__ Wp,
                       const float* __restrict__ bp, float* __restrict__ nf,
                       float* __restrict__ hid) {
    int w = (blockIdx.x * blockDim.x + threadIdx.x) >> 6;
    int lane = threadIdx.x & 63;
    if (w >= NN) return;
    const float* xr = x + (size_t)w * NI_;
    float x0 = xr[lane];
    float x1 = (lane < NI_ - 64) ? xr[64 + lane] : 0.f;
    float acc = bp[lane];
    const float* wr = Wp + (size_t)lane * NI_;
    #pragma unroll
    for (int i = 0; i < 64; i++) acc += __shfl(x0, i, 64) * wr[i];
    #pragma unroll
    for (int i = 0; i < NI_ - 64; i++) acc += __shfl(x1, i, 64) * wr[64 + i];
    acc = fmaxf(acc, 0.f);
    nf[(size_t)w * DD + lane] = acc;
    hid[(size_t)w * DD + lane] = acc;
}

__global__ void k_hist(const int* __restrict__ srcv, int* __restrict__ hist) {
    int e = blockIdx.x * blockDim.x + threadIdx.x;
    if (e < NE) atomicAdd(&hist[srcv[e]], 1);
}

// exclusive scan of hist -> rowptr[0..NN], cursor copy. Single block 1024 thr.
__global__ void k_scan(const int* __restrict__ hist, int* __restrict__ rowptr,
                       int* __restrict__ cursor) {
    __shared__ int part[1024];
    int t = threadIdx.x;
    const int PER = (NN + 1023) / 1024;
    int b0 = t * PER;
    int sum = 0;
    for (int i = 0; i < PER; i++) { int b = b0 + i; if (b < NN) sum += hist[b]; }
    part[t] = sum;
    __syncthreads();
    for (int off = 1; off < 1024; off <<= 1) {
        int v = (t >= off) ? part[t - off] : 0;
        __syncthreads();
        part[t] += v;
        __syncthreads();
    }
    int run = (t > 0) ? part[t - 1] : 0;
    for (int i = 0; i <= PER; i++) {
        int b = b0 + i;
        if (b <= NN) {
            rowptr[b] = run;
            if (b < NN) cursor[b] = run;
        }
        if (b < NN && i < PER) run += hist[b];
        if (i == PER) break;
    }
}

__global__ void k_scatter(const int* __restrict__ srcv, const int* __restrict__ dstv,
                          int* __restrict__ cursor, int* __restrict__ perm,
                          int* __restrict__ dsts_s) {
    int e = blockIdx.x * blockDim.x + threadIdx.x;
    if (e >= NE) return;
    int s = srcv[e];
    int pos = atomicAdd(&cursor[s], 1);
    perm[pos] = e;
    dsts_s[pos] = dstv[e];
}

// eh (sorted order, bf16) = relu(edge_attr[perm[p]] @ W_e1^T + b_e1).
__global__ void k_eh_s(const float* __restrict__ ea, const float* __restrict__ W1,
                       const float* __restrict__ b1, const int* __restrict__ perm,
                       unsigned short* __restrict__ ehs) {
    __shared__ float s_ea[2][EI_];
    __shared__ float s_W[EH_ * EI_];
    int t = threadIdx.x;
    for (int i = t; i < EH_ * EI_; i += 256) s_W[i] = W1[i];
    int p0 = blockIdx.x * 2;
    if (t < 2 * EI_) {
        int pp = p0 + t / EI_;
        int ee = (pp < NE) ? perm[pp] : 0;
        s_ea[t / EI_][t % EI_] = (pp < NE) ? ea[(size_t)ee * EI_ + t % EI_] : 0.f;
    }
    __syncthreads();
    int le = t >> 7;
    int h = t & 127;
    int p = p0 + le;
    if (p >= NE) return;
    float acc = b1[h];
    #pragma unroll
    for (int i = 0; i < EI_; i++) acc += s_ea[le][i] * s_W[h * EI_ + i];
    ehs[(size_t)p * EH_ + h] = f2b(fmaxf(acc, 0.f));
}

// Pack W_e2 into bf16 MFMA B-fragment order.
// Bpk[ct*1024 + t*512 + g*128 + n*8 + j] = bf16(B[d][c]), d=t*32+g*8+j, c=ct*16+n,
// B[d][h*64+f] = W_e2[(d*64+f)*128+h].
__global__ void k_pB(const float* __restrict__ W2, unsigned short* __restrict__ Bpk) {
    int idx = blockIdx.x * 256 + threadIdx.x;
    if (idx >= DD * EH_ * DD) return;
    int j = idx & 7;
    int n = (idx >> 3) & 15;
    int gg = idx >> 7;
    int g = gg & 3;
    int tt = gg >> 2;
    int t = tt & 1;
    int ct = tt >> 1;
    int d = t * 32 + g * 8 + j;
    int c = ct * 16 + n;
    int h = c >> 6, f = c & 63;
    Bpk[idx] = f2b(W2[((size_t)(d * 64 + f)) * EH_ + h]);
}

__global__ void k_tG(const float* __restrict__ W, float* __restrict__ Wt) {
    int idx = blockIdx.x * 256 + threadIdx.x;
    if (idx >= 192 * 64) return;
    int j = idx / 64, d2 = idx % 64;
    Wt[d2 * 192 + j] = W[idx];
}

// 64x64 transpose: Wt[c*64+r] = W[r*64+c]
__global__ void k_tr64(const float* __restrict__ W, float* __restrict__ Wt) {
    int idx = blockIdx.x * 256 + threadIdx.x;
    if (idx >= 64 * 64) return;
    int r = idx >> 6, c = idx & 63;
    Wt[c * 64 + r] = W[idx];
}

__global__ void k_cnt(const int* __restrict__ dstv, float* __restrict__ cnt) {
    int e = blockIdx.x * blockDim.x + threadIdx.x;
    if (e < NE) atomicAdd(&cnt[dstv[e]], 1.0f);
}

// xp = nf @ W_lin^T + b_lin (-> bf16 xpb); btp = xp @ reshape(b_e2,64,64); agg = 0.
// 4 nodes per wave to amortize weight reads.
__global__ void k_xp(const float* __restrict__ nf, const float* __restrict__ WlT,
                     const float* __restrict__ bl, const float* __restrict__ be2,
                     unsigned short* __restrict__ xpb, float* __restrict__ btp,
                     float* __restrict__ agg) {
    int wid = (blockIdx.x * blockDim.x + threadIdx.x) >> 6;
    int lane = threadIdx.x & 63;
    int s0 = wid * 4;
    if (s0 >= NN) return;
    int nv = (NN - s0 < 4) ? (NN - s0) : 4;
    float nvv[4], acc[4], bt[4];
    float blv = bl[lane];
    #pragma unroll
    for (int i = 0; i < 4; i++) {
        int s = s0 + (i < nv ? i : nv - 1);
        nvv[i] = nf[(size_t)s * DD + lane];
        acc[i] = blv;
        bt[i] = 0.f;
    }
    for (int d = 0; d < 64; d++) {
        float wv = WlT[d * 64 + lane];
        #pragma unroll
        for (int i = 0; i < 4; i++)
            acc[i] = fmaf(__shfl(nvv[i], d, 64), wv, acc[i]);
    }
    for (int d = 0; d < 64; d++) {
        float bv = be2[d * 64 + lane];
        #pragma unroll
        for (int i = 0; i < 4; i++)
            bt[i] = fmaf(__shfl(acc[i], d, 64), bv, bt[i]);
    }
    #pragma unroll
    for (int i = 0; i < 4; i++) {
        if (i < nv) {
            xpb[(size_t)(s0 + i) * DD + lane] = f2b(acc[i]);
            btp[(size_t)(s0 + i) * DD + lane] = bt[i];
            agg[(size_t)(s0 + i) * DD + lane] = 0.f;
        }
    }
}

// MFMA GEMM producing h-octet-blocked layout:
// Vt[l][hb][f][hq] (ushort idx = l*8192 + hb*512 + f*8 + hq), h = hb*8+hq.
// grid (chnp/256, 64): blockIdx.y -> hb = y>>2 (8 h each), fb = y&3 (16 f each).
// Block: 256 rows x (8 h x 16 f). Stores direct from registers, coalesced 16B/lane.
__global__ void k_V(const unsigned short* __restrict__ xpb,
                    const unsigned short* __restrict__ Bpk,
                    unsigned short* __restrict__ Vt, int c0) {
    int yb = blockIdx.y;
    int hb = yb >> 2, fb = yb & 3;
    int w = threadIdx.x >> 6;
    int lane = threadIdx.x & 63;
    int g = lane >> 4, n = lane & 15;
    bf16x8 B0[8], B1[8];
    #pragma unroll
    for (int q = 0; q < 8; q++) {
        int ct = (hb * 8 + q) * 4 + fb;
        const unsigned short* bp = Bpk + (size_t)ct * 1024 + g * 128 + n * 8;
        B0[q] = *(const bf16x8*)bp;
        B1[q] = *(const bf16x8*)(bp + 512);
    }
    int r0 = blockIdx.x * 256 + w * 64;
    #pragma unroll
    for (int mt = 0; mt < 4; mt++) {
        int row = r0 + mt * 16 + n;
        const unsigned short* ap = xpb + (size_t)(c0 + row) * DD + g * 8;
        bf16x8 a0 = *(const bf16x8*)ap;
        bf16x8 a1 = *(const bf16x8*)(ap + 32);
        f32x4 acc[8];
        #pragma unroll
        for (int q = 0; q < 8; q++) {
            f32x4 t = {0.f, 0.f, 0.f, 0.f};
            t = __builtin_amdgcn_mfma_f32_16x16x32_bf16(a0, B0[q], t, 0, 0, 0);
            t = __builtin_amdgcn_mfma_f32_16x16x32_bf16(a1, B1[q], t, 0, 0, 0);
            acc[q] = t;
        }
        #pragma unroll
        for (int rg = 0; rg < 4; rg++) {
            bf16x8 v;
            #pragma unroll
            for (int q = 0; q < 8; q++) v[q] = (short)f2b(acc[q][rg]);
            *(bf16x8*)(Vt + (size_t)(r0 + mt * 16 + g * 4 + rg) * 8192
                          + hb * 512 + (fb * 16 + n) * 8) = v;
        }
    }
}

// MFMA edge kernel: one wave per node. Per <=16-edge group:
// msg(16 x 64f) = eh_rows(16 x 128h) @ Vt[s](128h x 64f) via 4 ks x 4 nt MFMAs.
__global__ void k_edge_m(const int* __restrict__ rowptr, const int* __restrict__ dsts,
                         const unsigned short* __restrict__ ehs,
                         const unsigned short* __restrict__ Vt,
                         const float* __restrict__ btp, float* __restrict__ agg,
                         int c0, int c1) {
    int wid = (blockIdx.x * blockDim.x + threadIdx.x) >> 6;
    int lane = threadIdx.x & 63;
    int g = lane >> 4, n = lane & 15;
    int s = c0 + wid;
    if (s >= c1) return;
    int r0 = __builtin_amdgcn_readfirstlane(rowptr[s]);
    int r1 = __builtin_amdgcn_readfirstlane(rowptr[s + 1]);
    if (r0 == r1) return;
    const unsigned short* Vrow = Vt + (size_t)(s - c0) * 8192;
    bf16x8 Bf[4][4];
    #pragma unroll
    for (int ks = 0; ks < 4; ks++)
        #pragma unroll
        for (int nt = 0; nt < 4; nt++)
            Bf[ks][nt] = *(const bf16x8*)(Vrow + (ks * 4 + g) * 512 + (nt * 16 + n) * 8);
    float btv[4];
    #pragma unroll
    for (int nt = 0; nt < 4; nt++) btv[nt] = btp[(size_t)s * DD + nt * 16 + n];
    for (int base = r0; base < r1; base += 16) {
        int cntg = r1 - base; if (cntg > 16) cntg = 16;
        const unsigned short* ep = ehs + (size_t)(base + n) * EH_ + g * 8;
        f32x4 acc[4];
        #pragma unroll
        for (int nt = 0; nt < 4; nt++) { f32x4 z = {0.f, 0.f, 0.f, 0.f}; acc[nt] = z; }
        #pragma unroll
        for (int ks = 0; ks < 4; ks++) {
            bf16x8 a = *(const bf16x8*)(ep + ks * 32);
            #pragma unroll
            for (int nt = 0; nt < 4; nt++)
                acc[nt] = __builtin_amdgcn_mfma_f32_16x16x32_bf16(a, Bf[ks][nt], acc[nt], 0, 0, 0);
        }
        int dnr[4];
        #pragma unroll
        for (int rg = 0; rg < 4; rg++) {
            int m = g * 4 + rg;
            dnr[rg] = (m < cntg) ? dsts[base + m] : -1;
        }
        #pragma unroll
        for (int nt = 0; nt < 4; nt++)
            #pragma unroll
            for (int rg = 0; rg < 4; rg++)
                if (dnr[rg] >= 0)
                    atomicAdd(&agg[(size_t)dnr[rg] * DD + nt * 16 + n], acc[nt][rg] + btv[nt]);
    }
}

// nf = relu(agg/max(cnt,1)); GRU(nf, hidden) -> out. 4 nodes per wave.
__global__ void k_gru(const float* __restrict__ agg, const float* __restrict__ cnt,
                      const float* __restrict__ hid,
                      const float* __restrict__ WihT, const float* __restrict__ WhhT,
                      const float* __restrict__ bih, const float* __restrict__ bhh,
                      float* __restrict__ out_nf) {
    int wid = (blockIdx.x * blockDim.x + threadIdx.x) >> 6;
    int lane = threadIdx.x & 63;
    int s0 = wid * 4;
    if (s0 >= NN) return;
    int nv = (NN - s0 < 4) ? (NN - s0) : 4;
    float nfv[4], hv[4], gr[4], gz[4], gn[4], hr[4], hz[4], hn[4];
    float bi0 = bih[lane], bi1 = bih[64 + lane], bi2 = bih[128 + lane];
    float bh0 = bhh[lane], bh1 = bhh[64 + lane], bh2 = bhh[128 + lane];
    #pragma unroll
    for (int i = 0; i < 4; i++) {
        int s = s0 + (i < nv ? i : nv - 1);
        float c = fmaxf(cnt[s], 1.f);
        nfv[i] = fmaxf(agg[(size_t)s * DD + lane] / c, 0.f);
        hv[i] = hid[(size_t)s * DD + lane];
        gr[i] = bi0; gz[i] = bi1; gn[i] = bi2;
        hr[i] = bh0; hz[i] = bh1; hn[i] = bh2;
    }
    for (int d = 0; d < 64; d++) {
        const float* wi = WihT + d * 192;
        const float* wh = WhhT + d * 192;
        float wi0 = wi[lane], wi1 = wi[64 + lane], wi2 = wi[128 + lane];
        float wh0 = wh[lane], wh1 = wh[64 + lane], wh2 = wh[128 + lane];
        #pragma unroll
        for (int i = 0; i < 4; i++) {
            float nd = __shfl(nfv[i], d, 64);
            float hd = __shfl(hv[i], d, 64);
            gr[i] = fmaf(nd, wi0, gr[i]);
            gz[i] = fmaf(nd, wi1, gz[i]);
            gn[i] = fmaf(nd, wi2, gn[i]);
            hr[i] = fmaf(hd, wh0, hr[i]);
            hz[i] = fmaf(hd, wh1, hz[i]);
            hn[i] = fmaf(hd, wh2, hn[i]);
        }
    }
    for (int i = 0; i < nv; i++) {
        float r = 1.f / (1.f + __expf(-(gr[i] + hr[i])));
        float z = 1.f / (1.f + __expf(-(gz[i] + hz[i])));
        float nn2 = tanhf(gn[i] + r * hn[i]);
        out_nf[(size_t)(s0 + i) * DD + lane] = (1.f - z) * nn2 + z * hv[i];
    }
}

extern "C" void kernel_launch(void* const* d_in, const int* in_sizes, int n_in,
                              void* d_out, int out_size, void* d_ws, size_t ws_size,
                              hipStream_t stream) {
    const float* x   = (const float*)d_in[0];
    const int*   ei  = (const int*)d_in[1];
    const float* ea  = (const float*)d_in[2];
    const float* Wp  = (const float*)d_in[3];
    const float* bp  = (const float*)d_in[4];
    const float* W1  = (const float*)d_in[5];
    const float* b1  = (const float*)d_in[6];
    const float* W2  = (const float*)d_in[7];
    const float* b2  = (const float*)d_in[8];
    const float* Wl  = (const float*)d_in[9];
    const float* bl  = (const float*)d_in[10];
    const float* Wih = (const float*)d_in[11];
    const float* Whh = (const float*)d_in[12];
    const float* bih = (const float*)d_in[13];
    const float* bhh = (const float*)d_in[14];
    const int* srcv = ei;
    const int* dstv = ei + NE;

    float* p = (float*)d_ws;
    size_t off = 0;
    auto alloc = [&](size_t n) { n = (n + 3) & ~(size_t)3; float* q = p + off; off += n; return q; };
    float* nf   = alloc((size_t)NN * DD);
    float* hid  = alloc((size_t)NN * DD);
    float* btp  = alloc((size_t)NN * DD);
    float* agg  = alloc((size_t)NN * DD);
    float* cnt  = alloc(NN);
    unsigned short* ehs = (unsigned short*)alloc((size_t)(NE + 16) * EH_ / 2);  // bf16
    float* WihT = alloc(192 * 64);
    float* WhhT = alloc(192 * 64);
    float* WlT  = alloc(64 * 64);
    int* hist   = (int*)alloc(NN);
    int* rowptr = (int*)alloc(NN + 1);
    int* cursor = (int*)alloc(NN);
    int* perm   = (int*)alloc(NE);
    int* dsts_s = (int*)alloc(NE);
    unsigned short* Bpk = (unsigned short*)alloc((size_t)DD * EH_ * DD / 2);   // bf16
    unsigned short* xpb = (unsigned short*)alloc((size_t)PADN * DD / 2);       // bf16

    size_t used = off;
    size_t availf = (ws_size / 4 > used) ? (ws_size / 4 - used) : 0;
    long long rows_cap = (long long)(availf / 4096);
    int CH = (int)((rows_cap / 256) * 256);
    if (CH > PADN) CH = PADN;
    if (CH < 256) CH = 256;   // assumes ws >= ~80 MB
    unsigned short* Vt = (unsigned short*)alloc((size_t)CH * 8192 / 2);        // bf16

    // ---- one-time preprocessing ----
    k_zero<<<(NN + 255) / 256, 256, 0, stream>>>(cnt, NN);
    k_zero<<<(NN + 255) / 256, 256, 0, stream>>>((float*)hist, NN);
    k_proj<<<(NN + 3) / 4, 256, 0, stream>>>(x, Wp, bp, nf, hid);
    k_pB<<<(DD * EH_ * DD + 255) / 256, 256, 0, stream>>>(W2, Bpk);
    k_tG<<<48, 256, 0, stream>>>(Wih, WihT);
    k_tG<<<48, 256, 0, stream>>>(Whh, WhhT);
    k_tr64<<<16, 256, 0, stream>>>(Wl, WlT);
    k_cnt<<<(NE + 255) / 256, 256, 0, stream>>>(dstv, cnt);
    k_hist<<<(NE + 255) / 256, 256, 0, stream>>>(srcv, hist);
    k_scan<<<1, 1024, 0, stream>>>(hist, rowptr, cursor);
    k_scatter<<<(NE + 255) / 256, 256, 0, stream>>>(srcv, dstv, cursor, perm, dsts_s);
    k_eh_s<<<(NE + 1) / 2, 256, 0, stream>>>(ea, W1, b1, perm, ehs);

    int nc = (PADN + CH - 1) / CH;
    const int nw_quarter = (NN + 3) / 4;          // waves for 4-node-per-wave kernels
    for (int s = 0; s < NSTEPS; s++) {
        k_xp<<<(nw_quarter + 3) / 4, 256, 0, stream>>>(nf, WlT, bl, b2, xpb, btp, agg);
        for (int c = 0; c < nc; c++) {
            int c0 = c * CH;
            int chnp = (c0 + CH < PADN) ? CH : (PADN - c0);
            dim3 g(chnp / 256, 64);
            k_V<<<g, 256, 0, stream>>>(xpb, Bpk, Vt, c0);
            int c1e = (c0 + CH < NN) ? (c0 + CH) : NN;
            if (c0 < NN)
                k_edge_m<<<((c1e - c0) + 3) / 4, 256, 0, stream>>>(rowptr, dsts_s, ehs, Vt,
                                                                   btp, agg, c0, c1e);
        }
        float* dest = (s == NSTEPS - 1) ? (float*)d_out : nf;
        k_gru<<<(nw_quarter + 3) / 4, 256, 0, stream>>>(agg, cnt, hid, WihT, WhhT,
                                                        bih, bhh, dest);
    }
}

// Round 7
// 1119.488 us; speedup vs baseline: 1.0072x; 1.0072x over previous
//
#include <hip/hip_runtime.h>
#include <hip/hip_bf16.h>

#define NN 10000     // nodes
#define NE 100000    // edges
#define DD 64        // node_out_feats
#define EH_ 128      // edge_hidden_feats
#define NI_ 74       // node_in_feats
#define EI_ 12       // edge_in_feats
#define NSTEPS 6
#define PADN 10240

typedef short bf16x8 __attribute__((ext_vector_type(8)));
typedef float f32x4 __attribute__((ext_vector_type(4)));

static __device__ __forceinline__ unsigned short f2b(float f) {
    unsigned int u = __float_as_uint(f);
    u += 0x7fffu + ((u >> 16) & 1u);
    return (unsigned short)(u >> 16);
}

__global__ void k_zero(float* p, int n) {
    int i = blockIdx.x * blockDim.x + threadIdx.x;
    if (i < n) p[i] = 0.f;
}

// node_feats = relu(x @ W_proj^T + b_proj); hidden = node_feats. One wave per node.
__global__ void k_proj(const float* __restrict__ x, const float* __restrict__ Wp,
                       const float* __restrict__ bp, float* __restrict__ nf,
                       float* __restrict__ hid) {
    int w = (blockIdx.x * blockDim.x + threadIdx.x) >> 6;
    int lane = threadIdx.x & 63;
    if (w >= NN) return;
    const float* xr = x + (size_t)w * NI_;
    float x0 = xr[lane];
    float x1 = (lane < NI_ - 64) ? xr[64 + lane] : 0.f;
    float acc = bp[lane];
    const float* wr = Wp + (size_t)lane * NI_;
    #pragma unroll
    for (int i = 0; i < 64; i++) acc += __shfl(x0, i, 64) * wr[i];
    #pragma unroll
    for (int i = 0; i < NI_ - 64; i++) acc += __shfl(x1, i, 64) * wr[64 + i];
    acc = fmaxf(acc, 0.f);
    nf[(size_t)w * DD + lane] = acc;
    hid[(size_t)w * DD + lane] = acc;
}

__global__ void k_hist(const int* __restrict__ srcv, int* __restrict__ hist) {
    int e = blockIdx.x * blockDim.x + threadIdx.x;
    if (e < NE) atomicAdd(&hist[srcv[e]], 1);
}

// exclusive scan of hist -> rowptr[0..NN], cursor copy. Single block 1024 thr.
__global__ void k_scan(const int* __restrict__ hist, int* __restrict__ rowptr,
                       int* __restrict__ cursor) {
    __shared__ int part[1024];
    int t = threadIdx.x;
    const int PER = (NN + 1023) / 1024;
    int b0 = t * PER;
    int sum = 0;
    for (int i = 0; i < PER; i++) { int b = b0 + i; if (b < NN) sum += hist[b]; }
    part[t] = sum;
    __syncthreads();
    for (int off = 1; off < 1024; off <<= 1) {
        int v = (t >= off) ? part[t - off] : 0;
        __syncthreads();
        part[t] += v;
        __syncthreads();
    }
    int run = (t > 0) ? part[t - 1] : 0;
    for (int i = 0; i <= PER; i++) {
        int b = b0 + i;
        if (b <= NN) {
            rowptr[b] = run;
            if (b < NN) cursor[b] = run;
        }
        if (b < NN && i < PER) run += hist[b];
        if (i == PER) break;
    }
}

__global__ void k_scatter(const int* __restrict__ srcv, const int* __restrict__ dstv,
                          int* __restrict__ cursor, int* __restrict__ perm,
                          int* __restrict__ dsts_s) {
    int e = blockIdx.x * blockDim.x + threadIdx.x;
    if (e >= NE) return;
    int s = srcv[e];
    int pos = atomicAdd(&cursor[s], 1);
    perm[pos] = e;
    dsts_s[pos] = dstv[e];
}

// eh (sorted order, bf16) = relu(edge_attr[perm[p]] @ W_e1^T + b_e1).
__global__ void k_eh_s(const float* __restrict__ ea, const float* __restrict__ W1,
                       const float* __restrict__ b1, const int* __restrict__ perm,
                       unsigned short* __restrict__ ehs) {
    __shared__ float s_ea[2][EI_];
    __shared__ float s_W[EH_ * EI_];
    int t = threadIdx.x;
    for (int i = t; i < EH_ * EI_; i += 256) s_W[i] = W1[i];
    int p0 = blockIdx.x * 2;
    if (t < 2 * EI_) {
        int pp = p0 + t / EI_;
        int ee = (pp < NE) ? perm[pp] : 0;
        s_ea[t / EI_][t % EI_] = (pp < NE) ? ea[(size_t)ee * EI_ + t % EI_] : 0.f;
    }
    __syncthreads();
    int le = t >> 7;
    int h = t & 127;
    int p = p0 + le;
    if (p >= NE) return;
    float acc = b1[h];
    #pragma unroll
    for (int i = 0; i < EI_; i++) acc += s_ea[le][i] * s_W[h * EI_ + i];
    ehs[(size_t)p * EH_ + h] = f2b(fmaxf(acc, 0.f));
}

// Pack W_e2 into bf16 MFMA B-fragment order.
// Bpk[ct*1024 + t*512 + g*128 + n*8 + j] = bf16(B[d][c]), d=t*32+g*8+j, c=ct*16+n,
// B[d][h*64+f] = W_e2[(d*64+f)*128+h].
__global__ void k_pB(const float* __restrict__ W2, unsigned short* __restrict__ Bpk) {
    int idx = blockIdx.x * 256 + threadIdx.x;
    if (idx >= DD * EH_ * DD) return;
    int j = idx & 7;
    int n = (idx >> 3) & 15;
    int gg = idx >> 7;
    int g = gg & 3;
    int tt = gg >> 2;
    int t = tt & 1;
    int ct = tt >> 1;
    int d = t * 32 + g * 8 + j;
    int c = ct * 16 + n;
    int h = c >> 6, f = c & 63;
    Bpk[idx] = f2b(W2[((size_t)(d * 64 + f)) * EH_ + h]);
}

__global__ void k_tG(const float* __restrict__ W, float* __restrict__ Wt) {
    int idx = blockIdx.x * 256 + threadIdx.x;
    if (idx >= 192 * 64) return;
    int j = idx / 64, d2 = idx % 64;
    Wt[d2 * 192 + j] = W[idx];
}

// 64x64 transpose: Wt[c*64+r] = W[r*64+c]
__global__ void k_tr64(const float* __restrict__ W, float* __restrict__ Wt) {
    int idx = blockIdx.x * 256 + threadIdx.x;
    if (idx >= 64 * 64) return;
    int r = idx >> 6, c = idx & 63;
    Wt[c * 64 + r] = W[idx];
}

__global__ void k_cnt(const int* __restrict__ dstv, float* __restrict__ cnt) {
    int e = blockIdx.x * blockDim.x + threadIdx.x;
    if (e < NE) atomicAdd(&cnt[dstv[e]], 1.0f);
}

// xp = nf @ W_lin^T + b_lin (-> bf16 xpb); btp = xp @ reshape(b_e2,64,64); agg = 0.
// 4 nodes per wave. Used once before the step loop.
__global__ void k_xp(const float* __restrict__ nf, const float* __restrict__ WlT,
                     const float* __restrict__ bl, const float* __restrict__ be2,
                     unsigned short* __restrict__ xpb, float* __restrict__ btp,
                     float* __restrict__ agg) {
    int wid = (blockIdx.x * blockDim.x + threadIdx.x) >> 6;
    int lane = threadIdx.x & 63;
    int s0 = wid * 4;
    if (s0 >= NN) return;
    int nv = (NN - s0 < 4) ? (NN - s0) : 4;
    float nvv[4], acc[4], bt[4];
    float blv = bl[lane];
    #pragma unroll
    for (int i = 0; i < 4; i++) {
        int s = s0 + (i < nv ? i : nv - 1);
        nvv[i] = nf[(size_t)s * DD + lane];
        acc[i] = blv;
        bt[i] = 0.f;
    }
    for (int d = 0; d < 64; d++) {
        float wv = WlT[d * 64 + lane];
        #pragma unroll
        for (int i = 0; i < 4; i++)
            acc[i] = fmaf(__shfl(nvv[i], d, 64), wv, acc[i]);
    }
    for (int d = 0; d < 64; d++) {
        float bv = be2[d * 64 + lane];
        #pragma unroll
        for (int i = 0; i < 4; i++)
            bt[i] = fmaf(__shfl(acc[i], d, 64), bv, bt[i]);
    }
    #pragma unroll
    for (int i = 0; i < 4; i++) {
        if (i < nv) {
            xpb[(size_t)(s0 + i) * DD + lane] = f2b(acc[i]);
            btp[(size_t)(s0 + i) * DD + lane] = bt[i];
            agg[(size_t)(s0 + i) * DD + lane] = 0.f;
        }
    }
}

// MFMA GEMM producing h-octet-blocked layout:
// Vt[l][hb][f][hq] (ushort idx = l*8192 + hb*512 + f*8 + hq), h = hb*8+hq.
// grid (chnp/256, 64): blockIdx.y -> hb = y>>2 (8 h each), fb = y&3 (16 f each).
// Nontemporal stores: V is produced once, consumed once -> bypass L2.
__global__ void k_V(const unsigned short* __restrict__ xpb,
                    const unsigned short* __restrict__ Bpk,
                    unsigned short* __restrict__ Vt, int c0) {
    int yb = blockIdx.y;
    int hb = yb >> 2, fb = yb & 3;
    int w = threadIdx.x >> 6;
    int lane = threadIdx.x & 63;
    int g = lane >> 4, n = lane & 15;
    bf16x8 B0[8], B1[8];
    #pragma unroll
    for (int q = 0; q < 8; q++) {
        int ct = (hb * 8 + q) * 4 + fb;
        const unsigned short* bp = Bpk + (size_t)ct * 1024 + g * 128 + n * 8;
        B0[q] = *(const bf16x8*)bp;
        B1[q] = *(const bf16x8*)(bp + 512);
    }
    int r0 = blockIdx.x * 256 + w * 64;
    #pragma unroll
    for (int mt = 0; mt < 4; mt++) {
        int row = r0 + mt * 16 + n;
        const unsigned short* ap = xpb + (size_t)(c0 + row) * DD + g * 8;
        bf16x8 a0 = *(const bf16x8*)ap;
        bf16x8 a1 = *(const bf16x8*)(ap + 32);
        f32x4 acc[8];
        #pragma unroll
        for (int q = 0; q < 8; q++) {
            f32x4 t = {0.f, 0.f, 0.f, 0.f};
            t = __builtin_amdgcn_mfma_f32_16x16x32_bf16(a0, B0[q], t, 0, 0, 0);
            t = __builtin_amdgcn_mfma_f32_16x16x32_bf16(a1, B1[q], t, 0, 0, 0);
            acc[q] = t;
        }
        #pragma unroll
        for (int rg = 0; rg < 4; rg++) {
            bf16x8 v;
            #pragma unroll
            for (int q = 0; q < 8; q++) v[q] = (short)f2b(acc[q][rg]);
            __builtin_nontemporal_store(v,
                (bf16x8*)(Vt + (size_t)(r0 + mt * 16 + g * 4 + rg) * 8192
                             + hb * 512 + (fb * 16 + n) * 8));
        }
    }
}

// MFMA edge kernel: one wave per node. Per <=16-edge group:
// msg(16 x 64f) = eh_rows(16 x 128h) @ Vt[s](128h x 64f) via 4 ks x 4 nt MFMAs.
// V fragments loaded nontemporal (read-once stream).
__global__ void k_edge_m(const int* __restrict__ rowptr, const int* __restrict__ dsts,
                         const unsigned short* __restrict__ ehs,
                         const unsigned short* __restrict__ Vt,
                         const float* __restrict__ btp, float* __restrict__ agg,
                         int c0, int c1) {
    int wid = (blockIdx.x * blockDim.x + threadIdx.x) >> 6;
    int lane = threadIdx.x & 63;
    int g = lane >> 4, n = lane & 15;
    int s = c0 + wid;
    if (s >= c1) return;
    int r0 = __builtin_amdgcn_readfirstlane(rowptr[s]);
    int r1 = __builtin_amdgcn_readfirstlane(rowptr[s + 1]);
    if (r0 == r1) return;
    const unsigned short* Vrow = Vt + (size_t)(s - c0) * 8192;
    bf16x8 Bf[4][4];
    #pragma unroll
    for (int ks = 0; ks < 4; ks++)
        #pragma unroll
        for (int nt = 0; nt < 4; nt++)
            Bf[ks][nt] = __builtin_nontemporal_load(
                (const bf16x8*)(Vrow + (ks * 4 + g) * 512 + (nt * 16 + n) * 8));
    float btv[4];
    #pragma unroll
    for (int nt = 0; nt < 4; nt++) btv[nt] = btp[(size_t)s * DD + nt * 16 + n];
    for (int base = r0; base < r1; base += 16) {
        int cntg = r1 - base; if (cntg > 16) cntg = 16;
        const unsigned short* ep = ehs + (size_t)(base + n) * EH_ + g * 8;
        f32x4 acc[4];
        #pragma unroll
        for (int nt = 0; nt < 4; nt++) { f32x4 z = {0.f, 0.f, 0.f, 0.f}; acc[nt] = z; }
        #pragma unroll
        for (int ks = 0; ks < 4; ks++) {
            bf16x8 a = *(const bf16x8*)(ep + ks * 32);
            #pragma unroll
            for (int nt = 0; nt < 4; nt++)
                acc[nt] = __builtin_amdgcn_mfma_f32_16x16x32_bf16(a, Bf[ks][nt], acc[nt], 0, 0, 0);
        }
        int dnr[4];
        #pragma unroll
        for (int rg = 0; rg < 4; rg++) {
            int m = g * 4 + rg;
            dnr[rg] = (m < cntg) ? dsts[base + m] : -1;
        }
        #pragma unroll
        for (int nt = 0; nt < 4; nt++)
            #pragma unroll
            for (int rg = 0; rg < 4; rg++)
                if (dnr[rg] >= 0)
                    atomicAdd(&agg[(size_t)dnr[rg] * DD + nt * 16 + n], acc[nt][rg] + btv[nt]);
    }
}

// Fused GRU + next-step xp. 4 nodes per wave.
// nf' = GRU(relu(agg/cnt), hid) -> out_nf; if doXp: xp = nf'@Wl^T+bl -> xpb,
// btp = xp@be2, agg = 0 (ready for next step).
__global__ void k_gruxp(const float* __restrict__ agg, const float* __restrict__ cnt,
                        const float* __restrict__ hid,
                        const float* __restrict__ WihT, const float* __restrict__ WhhT,
                        const float* __restrict__ bih, const float* __restrict__ bhh,
                        const float* __restrict__ WlT, const float* __restrict__ bl,
                        const float* __restrict__ be2,
                        float* __restrict__ out_nf,
                        unsigned short* __restrict__ xpb, float* __restrict__ btp,
                        float* __restrict__ aggw, int doXp) {
    int wid = (blockIdx.x * blockDim.x + threadIdx.x) >> 6;
    int lane = threadIdx.x & 63;
    int s0 = wid * 4;
    if (s0 >= NN) return;
    int nv = (NN - s0 < 4) ? (NN - s0) : 4;
    float nfv[4], hv[4], gr[4], gz[4], gn[4], hr[4], hz[4], hn[4];
    float bi0 = bih[lane], bi1 = bih[64 + lane], bi2 = bih[128 + lane];
    float bh0 = bhh[lane], bh1 = bhh[64 + lane], bh2 = bhh[128 + lane];
    #pragma unroll
    for (int i = 0; i < 4; i++) {
        int s = s0 + (i < nv ? i : nv - 1);
        float c = fmaxf(cnt[s], 1.f);
        nfv[i] = fmaxf(agg[(size_t)s * DD + lane] / c, 0.f);
        hv[i] = hid[(size_t)s * DD + lane];
        gr[i] = bi0; gz[i] = bi1; gn[i] = bi2;
        hr[i] = bh0; hz[i] = bh1; hn[i] = bh2;
    }
    for (int d = 0; d < 64; d++) {
        const float* wi = WihT + d * 192;
        const float* wh = WhhT + d * 192;
        float wi0 = wi[lane], wi1 = wi[64 + lane], wi2 = wi[128 + lane];
        float wh0 = wh[lane], wh1 = wh[64 + lane], wh2 = wh[128 + lane];
        #pragma unroll
        for (int i = 0; i < 4; i++) {
            float nd = __shfl(nfv[i], d, 64);
            float hd = __shfl(hv[i], d, 64);
            gr[i] = fmaf(nd, wi0, gr[i]);
            gz[i] = fmaf(nd, wi1, gz[i]);
            gn[i] = fmaf(nd, wi2, gn[i]);
            hr[i] = fmaf(hd, wh0, hr[i]);
            hz[i] = fmaf(hd, wh1, hz[i]);
            hn[i] = fmaf(hd, wh2, hn[i]);
        }
    }
    float newnf[4];
    #pragma unroll
    for (int i = 0; i < 4; i++) {
        float r = 1.f / (1.f + __expf(-(gr[i] + hr[i])));
        float z = 1.f / (1.f + __expf(-(gz[i] + hz[i])));
        float nn2 = tanhf(gn[i] + r * hn[i]);
        newnf[i] = (1.f - z) * nn2 + z * hv[i];
        if (i < nv) out_nf[(size_t)(s0 + i) * DD + lane] = newnf[i];
    }
    if (!doXp) return;
    float acc[4], bt[4];
    float blv = bl[lane];
    #pragma unroll
    for (int i = 0; i < 4; i++) { acc[i] = blv; bt[i] = 0.f; }
    for (int d = 0; d < 64; d++) {
        float wv = WlT[d * 64 + lane];
        #pragma unroll
        for (int i = 0; i < 4; i++)
            acc[i] = fmaf(__shfl(newnf[i], d, 64), wv, acc[i]);
    }
    for (int d = 0; d < 64; d++) {
        float bv = be2[d * 64 + lane];
        #pragma unroll
        for (int i = 0; i < 4; i++)
            bt[i] = fmaf(__shfl(acc[i], d, 64), bv, bt[i]);
    }
    #pragma unroll
    for (int i = 0; i < 4; i++) {
        if (i < nv) {
            xpb[(size_t)(s0 + i) * DD + lane] = f2b(acc[i]);
            btp[(size_t)(s0 + i) * DD + lane] = bt[i];
            aggw[(size_t)(s0 + i) * DD + lane] = 0.f;
        }
    }
}

extern "C" void kernel_launch(void* const* d_in, const int* in_sizes, int n_in,
                              void* d_out, int out_size, void* d_ws, size_t ws_size,
                              hipStream_t stream) {
    const float* x   = (const float*)d_in[0];
    const int*   ei  = (const int*)d_in[1];
    const float* ea  = (const float*)d_in[2];
    const float* Wp  = (const float*)d_in[3];
    const float* bp  = (const float*)d_in[4];
    const float* W1  = (const float*)d_in[5];
    const float* b1  = (const float*)d_in[6];
    const float* W2  = (const float*)d_in[7];
    const float* b2  = (const float*)d_in[8];
    const float* Wl  = (const float*)d_in[9];
    const float* bl  = (const float*)d_in[10];
    const float* Wih = (const float*)d_in[11];
    const float* Whh = (const float*)d_in[12];
    const float* bih = (const float*)d_in[13];
    const float* bhh = (const float*)d_in[14];
    const int* srcv = ei;
    const int* dstv = ei + NE;

    float* p = (float*)d_ws;
    size_t off = 0;
    auto alloc = [&](size_t n) { n = (n + 3) & ~(size_t)3; float* q = p + off; off += n; return q; };
    float* nf   = alloc((size_t)NN * DD);
    float* hid  = alloc((size_t)NN * DD);
    float* btp  = alloc((size_t)NN * DD);
    float* agg  = alloc((size_t)NN * DD);
    float* cnt  = alloc(NN);
    unsigned short* ehs = (unsigned short*)alloc((size_t)(NE + 16) * EH_ / 2);  // bf16
    float* WihT = alloc(192 * 64);
    float* WhhT = alloc(192 * 64);
    float* WlT  = alloc(64 * 64);
    int* hist   = (int*)alloc(NN);
    int* rowptr = (int*)alloc(NN + 1);
    int* cursor = (int*)alloc(NN);
    int* perm   = (int*)alloc(NE);
    int* dsts_s = (int*)alloc(NE);
    unsigned short* Bpk = (unsigned short*)alloc((size_t)DD * EH_ * DD / 2);   // bf16
    unsigned short* xpb = (unsigned short*)alloc((size_t)PADN * DD / 2);       // bf16

    size_t used = off;
    size_t availf = (ws_size / 4 > used) ? (ws_size / 4 - used) : 0;
    long long rows_cap = (long long)(availf / 4096);
    int CH = (int)((rows_cap / 256) * 256);
    if (CH > PADN) CH = PADN;
    if (CH < 256) CH = 256;   // assumes ws >= ~80 MB
    unsigned short* Vt = (unsigned short*)alloc((size_t)CH * 8192 / 2);        // bf16

    // ---- one-time preprocessing ----
    k_zero<<<(NN + 255) / 256, 256, 0, stream>>>(cnt, NN);
    k_zero<<<(NN + 255) / 256, 256, 0, stream>>>((float*)hist, NN);
    k_proj<<<(NN + 3) / 4, 256, 0, stream>>>(x, Wp, bp, nf, hid);
    k_pB<<<(DD * EH_ * DD + 255) / 256, 256, 0, stream>>>(W2, Bpk);
    k_tG<<<48, 256, 0, stream>>>(Wih, WihT);
    k_tG<<<48, 256, 0, stream>>>(Whh, WhhT);
    k_tr64<<<16, 256, 0, stream>>>(Wl, WlT);
    k_cnt<<<(NE + 255) / 256, 256, 0, stream>>>(dstv, cnt);
    k_hist<<<(NE + 255) / 256, 256, 0, stream>>>(srcv, hist);
    k_scan<<<1, 1024, 0, stream>>>(hist, rowptr, cursor);
    k_scatter<<<(NE + 255) / 256, 256, 0, stream>>>(srcv, dstv, cursor, perm, dsts_s);
    k_eh_s<<<(NE + 1) / 2, 256, 0, stream>>>(ea, W1, b1, perm, ehs);

    int nc = (PADN + CH - 1) / CH;
    const int nw_quarter = (NN + 3) / 4;          // waves for 4-node-per-wave kernels
    k_xp<<<(nw_quarter + 3) / 4, 256, 0, stream>>>(nf, WlT, bl, b2, xpb, btp, agg);
    for (int s = 0; s < NSTEPS; s++) {
        for (int c = 0; c < nc; c++) {
            int c0 = c * CH;
            int chnp = (c0 + CH < PADN) ? CH : (PADN - c0);
            dim3 g(chnp / 256, 64);
            k_V<<<g, 256, 0, stream>>>(xpb, Bpk, Vt, c0);
            int c1e = (c0 + CH < NN) ? (c0 + CH) : NN;
            if (c0 < NN)
                k_edge_m<<<((c1e - c0) + 3) / 4, 256, 0, stream>>>(rowptr, dsts_s, ehs, Vt,
                                                                   btp, agg, c0, c1e);
        }
        float* dest = (s == NSTEPS - 1) ? (float*)d_out : nf;
        k_gruxp<<<(nw_quarter + 3) / 4, 256, 0, stream>>>(agg, cnt, hid, WihT, WhhT,
                                                          bih, bhh, WlT, bl, b2,
                                                          dest, xpb, btp, agg,
                                                          (s < NSTEPS - 1) ? 1 : 0);
    }
}

// Round 8
// 941.643 us; speedup vs baseline: 1.1974x; 1.1889x over previous
//
#include <hip/hip_runtime.h>
#include <hip/hip_bf16.h>

#define NN 10000     // nodes
#define NE 100000    // edges
#define DD 64        // node_out_feats
#define EH_ 128      // edge_hidden_feats
#define NI_ 74       // node_in_feats
#define EI_ 12       // edge_in_feats
#define NSTEPS 6
#define PADN 10240
#define GCAP 16384   // max groups (ceil-sum bound 15625)

typedef short bf16x8 __attribute__((ext_vector_type(8)));
typedef float f32x4 __attribute__((ext_vector_type(4)));

static __device__ __forceinline__ unsigned short f2b(float f) {
    unsigned int u = __float_as_uint(f);
    u += 0x7fffu + ((u >> 16) & 1u);
    return (unsigned short)(u >> 16);
}

__global__ void k_zero(float* p, int n) {
    int i = blockIdx.x * blockDim.x + threadIdx.x;
    if (i < n) p[i] = 0.f;
}

// node_feats = relu(x @ W_proj^T + b_proj); hidden = node_feats. One wave per node.
__global__ void k_proj(const float* __restrict__ x, const float* __restrict__ Wp,
                       const float* __restrict__ bp, float* __restrict__ nf,
                       float* __restrict__ hid) {
    int w = (blockIdx.x * blockDim.x + threadIdx.x) >> 6;
    int lane = threadIdx.x & 63;
    if (w >= NN) return;
    const float* xr = x + (size_t)w * NI_;
    float x0 = xr[lane];
    float x1 = (lane < NI_ - 64) ? xr[64 + lane] : 0.f;
    float acc = bp[lane];
    const float* wr = Wp + (size_t)lane * NI_;
    #pragma unroll
    for (int i = 0; i < 64; i++) acc += __shfl(x0, i, 64) * wr[i];
    #pragma unroll
    for (int i = 0; i < NI_ - 64; i++) acc += __shfl(x1, i, 64) * wr[64 + i];
    acc = fmaxf(acc, 0.f);
    nf[(size_t)w * DD + lane] = acc;
    hid[(size_t)w * DD + lane] = acc;
}

__global__ void k_hist(const int* __restrict__ srcv, int* __restrict__ hist) {
    int e = blockIdx.x * blockDim.x + threadIdx.x;
    if (e < NE) atomicAdd(&hist[srcv[e]], 1);
}

// exclusive scan of hist -> rowptr[0..NN], cursor copy. Single block 1024 thr.
__global__ void k_scan(const int* __restrict__ hist, int* __restrict__ rowptr,
                       int* __restrict__ cursor) {
    __shared__ int part[1024];
    int t = threadIdx.x;
    const int PER = (NN + 1023) / 1024;
    int b0 = t * PER;
    int sum = 0;
    for (int i = 0; i < PER; i++) { int b = b0 + i; if (b < NN) sum += hist[b]; }
    part[t] = sum;
    __syncthreads();
    for (int off = 1; off < 1024; off <<= 1) {
        int v = (t >= off) ? part[t - off] : 0;
        __syncthreads();
        part[t] += v;
        __syncthreads();
    }
    int run = (t > 0) ? part[t - 1] : 0;
    for (int i = 0; i <= PER; i++) {
        int b = b0 + i;
        if (b <= NN) {
            rowptr[b] = run;
            if (b < NN) cursor[b] = run;
        }
        if (b < NN && i < PER) run += hist[b];
        if (i == PER) break;
    }
}

__global__ void k_scatter(const int* __restrict__ srcv, const int* __restrict__ dstv,
                          int* __restrict__ cursor, int* __restrict__ perm,
                          int* __restrict__ dsts_s) {
    int e = blockIdx.x * blockDim.x + threadIdx.x;
    if (e >= NE) return;
    int s = srcv[e];
    int pos = atomicAdd(&cursor[s], 1);
    perm[pos] = e;
    dsts_s[pos] = dstv[e];
}

// Build group list: group = (src, base, cnt<=16) over src-sorted edge ranges.
// Single block 1024 threads, scan of per-node ceil(deg/16).
__global__ void k_grp(const int* __restrict__ rowptr, int* __restrict__ g_src,
                      int* __restrict__ g_base, int* __restrict__ g_cnt,
                      int* __restrict__ d_ng) {
    __shared__ int part[1024];
    int t = threadIdx.x;
    const int PER = (NN + 1023) / 1024;
    int b0 = t * PER;
    int cg = 0;
    for (int i = 0; i < PER; i++) {
        int b = b0 + i;
        if (b < NN) { int d = rowptr[b + 1] - rowptr[b]; cg += (d + 15) >> 4; }
    }
    part[t] = cg;
    __syncthreads();
    for (int off = 1; off < 1024; off <<= 1) {
        int v = (t >= off) ? part[t - off] : 0;
        __syncthreads();
        part[t] += v;
        __syncthreads();
    }
    int run = (t > 0) ? part[t - 1] : 0;
    for (int i = 0; i < PER; i++) {
        int b = b0 + i;
        if (b >= NN) break;
        int r0 = rowptr[b], r1 = rowptr[b + 1];
        for (int p = r0; p < r1; p += 16) {
            g_src[run] = b;
            g_base[run] = p;
            int c = r1 - p; if (c > 16) c = 16;
            g_cnt[run] = c;
            run++;
        }
    }
    if (t == 1023) *d_ng = run;
}

// eh (sorted order, bf16) = relu(edge_attr[perm[p]] @ W_e1^T + b_e1).
__global__ void k_eh_s(const float* __restrict__ ea, const float* __restrict__ W1,
                       const float* __restrict__ b1, const int* __restrict__ perm,
                       unsigned short* __restrict__ ehs) {
    __shared__ float s_ea[2][EI_];
    __shared__ float s_W[EH_ * EI_];
    int t = threadIdx.x;
    for (int i = t; i < EH_ * EI_; i += 256) s_W[i] = W1[i];
    int p0 = blockIdx.x * 2;
    if (t < 2 * EI_) {
        int pp = p0 + t / EI_;
        int ee = (pp < NE) ? perm[pp] : 0;
        s_ea[t / EI_][t % EI_] = (pp < NE) ? ea[(size_t)ee * EI_ + t % EI_] : 0.f;
    }
    __syncthreads();
    int le = t >> 7;
    int h = t & 127;
    int p = p0 + le;
    if (p >= NE) return;
    float acc = b1[h];
    #pragma unroll
    for (int i = 0; i < EI_; i++) acc += s_ea[le][i] * s_W[h * EI_ + i];
    ehs[(size_t)p * EH_ + h] = f2b(fmaxf(acc, 0.f));
}

// Pack W_e2 into bf16 MFMA A-fragment order for the fused kernel.
// Tile (ks,hB,f): A[row n = h-in-tile][k = d]; idx =
// ((((ks*2+hB)*64+f)*2+frag)*4+g)*128 + n*8 + j, d=frag*32+g*8+j, h=ks*32+hB*16+n.
__global__ void k_pA(const float* __restrict__ W2, unsigned short* __restrict__ Apk) {
    int idx = blockIdx.x * 256 + threadIdx.x;
    if (idx >= (1 << 19)) return;
    int j = idx & 7;
    int n = (idx >> 3) & 15;
    int g = (idx >> 7) & 3;
    int frag = (idx >> 9) & 1;
    int f = (idx >> 10) & 63;
    int hB = (idx >> 16) & 1;
    int ks = idx >> 17;
    int d = frag * 32 + g * 8 + j;
    int h = ks * 32 + hB * 16 + n;
    Apk[idx] = f2b(W2[((size_t)(d * 64 + f)) * EH_ + h]);
}

__global__ void k_tG(const float* __restrict__ W, float* __restrict__ Wt) {
    int idx = blockIdx.x * 256 + threadIdx.x;
    if (idx >= 192 * 64) return;
    int j = idx / 64, d2 = idx % 64;
    Wt[d2 * 192 + j] = W[idx];
}

__global__ void k_tr64(const float* __restrict__ W, float* __restrict__ Wt) {
    int idx = blockIdx.x * 256 + threadIdx.x;
    if (idx >= 64 * 64) return;
    int r = idx >> 6, c = idx & 63;
    Wt[c * 64 + r] = W[idx];
}

__global__ void k_cnt(const int* __restrict__ dstv, float* __restrict__ cnt) {
    int e = blockIdx.x * blockDim.x + threadIdx.x;
    if (e < NE) atomicAdd(&cnt[dstv[e]], 1.0f);
}

// xp = nf @ W_lin^T + b_lin (-> bf16 xpb); btp = xp @ reshape(b_e2,64,64); agg = 0.
__global__ void k_xp(const float* __restrict__ nf, const float* __restrict__ WlT,
                     const float* __restrict__ bl, const float* __restrict__ be2,
                     unsigned short* __restrict__ xpb, float* __restrict__ btp,
                     float* __restrict__ agg) {
    int wid = (blockIdx.x * blockDim.x + threadIdx.x) >> 6;
    int lane = threadIdx.x & 63;
    int s0 = wid * 4;
    if (s0 >= NN) return;
    int nv = (NN - s0 < 4) ? (NN - s0) : 4;
    float nvv[4], acc[4], bt[4];
    float blv = bl[lane];
    #pragma unroll
    for (int i = 0; i < 4; i++) {
        int s = s0 + (i < nv ? i : nv - 1);
        nvv[i] = nf[(size_t)s * DD + lane];
        acc[i] = blv;
        bt[i] = 0.f;
    }
    for (int d = 0; d < 64; d++) {
        float wv = WlT[d * 64 + lane];
        #pragma unroll
        for (int i = 0; i < 4; i++)
            acc[i] = fmaf(__shfl(nvv[i], d, 64), wv, acc[i]);
    }
    for (int d = 0; d < 64; d++) {
        float bv = be2[d * 64 + lane];
        #pragma unroll
        for (int i = 0; i < 4; i++)
            bt[i] = fmaf(__shfl(acc[i], d, 64), bv, bt[i]);
    }
    #pragma unroll
    for (int i = 0; i < 4; i++) {
        if (i < nv) {
            xpb[(size_t)(s0 + i) * DD + lane] = f2b(acc[i]);
            btp[(size_t)(s0 + i) * DD + lane] = bt[i];
            agg[(size_t)(s0 + i) * DD + lane] = 0.f;
        }
    }
}

// Fused V-GEMM + edge MFMA. Block = 4 waves, 16 groups.
// Per ks (32 h): phase A computes V-slice (16 nodes x 32h x 64f) into XOR-swizzled
// LDS via MFMA (rows=h, cols=node); phase B: per group, ds_read_b128 B-frags +
// edge MFMA (K=32) accumulating in registers across ks. Epilogue: masked atomics.
__global__ __launch_bounds__(256, 2) void k_fv(
        const unsigned short* __restrict__ xpb,
        const unsigned short* __restrict__ Apk,
        const int* __restrict__ g_src, const int* __restrict__ g_base,
        const int* __restrict__ g_cnt, const int* __restrict__ d_ng,
        const unsigned short* __restrict__ ehs, const int* __restrict__ dsts,
        const float* __restrict__ btp, float* __restrict__ agg) {
    __shared__ unsigned char lds[65536];
    int ng = *d_ng;
    int nb = blockIdx.x * 16;
    if (nb >= ng) return;
    int tid = threadIdx.x;
    int w = tid >> 6, lane = tid & 63;
    int g = lane >> 4, n = lane & 15;

    // xp B-fragments for the block's 16 slots (col n = slot)
    int srcn = g_src[nb + n];
    const unsigned short* xr = xpb + (size_t)srcn * DD + g * 8;
    bf16x8 xb0 = *(const bf16x8*)xr;
    bf16x8 xb1 = *(const bf16x8*)(xr + 32);

    // per-wave group metadata (uniform)
    int sq[4], bq[4], cq[4];
    #pragma unroll
    for (int q = 0; q < 4; q++) {
        int gi = nb + w * 4 + q;
        sq[q] = g_src[gi]; bq[q] = g_base[gi]; cq[q] = g_cnt[gi];
    }

    f32x4 acc[4][4];
    #pragma unroll
    for (int q = 0; q < 4; q++)
        #pragma unroll
        for (int nt = 0; nt < 4; nt++) {
            f32x4 z = {0.f, 0.f, 0.f, 0.f};
            acc[q][nt] = z;
        }

    for (int ks = 0; ks < 4; ks++) {
        if (ks) __syncthreads();
        // ---- phase A: V slice -> LDS ----
        #pragma unroll
        for (int hB = 0; hB < 2; hB++) {
            int ho = hB * 2 + (g >> 1);
            int hq0 = (g & 1) * 4;
            int abase = (n << 12) | (ho << 4) | (hq0 << 1);
            const unsigned short* apks =
                Apk + (size_t)((ks * 2 + hB) * 64 + (w << 4)) * 1024 + g * 128 + n * 8;
            #pragma unroll 8
            for (int fi = 0; fi < 16; fi++) {
                int f = (w << 4) + fi;
                const unsigned short* ap = apks + fi * 1024;
                bf16x8 A0 = *(const bf16x8*)ap;
                bf16x8 A1 = *(const bf16x8*)(ap + 512);
                f32x4 d = {0.f, 0.f, 0.f, 0.f};
                d = __builtin_amdgcn_mfma_f32_16x16x32_bf16(A0, xb0, d, 0, 0, 0);
                d = __builtin_amdgcn_mfma_f32_16x16x32_bf16(A1, xb1, d, 0, 0, 0);
                unsigned int lo = (unsigned)f2b(d[0]) | ((unsigned)f2b(d[1]) << 16);
                unsigned int hi = (unsigned)f2b(d[2]) | ((unsigned)f2b(d[3]) << 16);
                int addr = abase | (f << 6);
                addr ^= ((n ^ f) & 7) << 4;
                *(unsigned long long*)(lds + addr) =
                    (unsigned long long)lo | ((unsigned long long)hi << 32);
            }
        }
        // prefetch eh A-frags for this ks (no LDS dependency)
        bf16x8 aeh[4];
        #pragma unroll
        for (int q = 0; q < 4; q++)
            aeh[q] = *(const bf16x8*)(ehs + (size_t)(bq[q] + n) * EH_ + ks * 32 + g * 8);
        __syncthreads();
        // ---- phase B: edge MFMA from LDS ----
        #pragma unroll
        for (int q = 0; q < 4; q++) {
            if (cq[q] == 0) continue;
            int sl = w * 4 + q;
            #pragma unroll
            for (int nt = 0; nt < 4; nt++) {
                int f = nt * 16 + n;
                int addr = (sl << 12) | (f << 6) | (g << 4);
                addr ^= ((sl ^ f) & 7) << 4;
                bf16x8 Bf = *(const bf16x8*)(lds + addr);
                acc[q][nt] = __builtin_amdgcn_mfma_f32_16x16x32_bf16(aeh[q], Bf,
                                                                     acc[q][nt], 0, 0, 0);
            }
        }
    }
    // ---- epilogue: atomics ----
    #pragma unroll
    for (int q = 0; q < 4; q++) {
        if (cq[q] == 0) continue;
        #pragma unroll
        for (int nt = 0; nt < 4; nt++) {
            float btv = btp[(size_t)sq[q] * DD + nt * 16 + n];
            #pragma unroll
            for (int rg = 0; rg < 4; rg++) {
                int m = g * 4 + rg;
                if (m < cq[q]) {
                    int dn = dsts[bq[q] + m];
                    atomicAdd(&agg[(size_t)dn * DD + nt * 16 + n], acc[q][nt][rg] + btv);
                }
            }
        }
    }
}

// Fused GRU + next-step xp. 4 nodes per wave.
__global__ void k_gruxp(const float* __restrict__ agg, const float* __restrict__ cnt,
                        const float* __restrict__ hid,
                        const float* __restrict__ WihT, const float* __restrict__ WhhT,
                        const float* __restrict__ bih, const float* __restrict__ bhh,
                        const float* __restrict__ WlT, const float* __restrict__ bl,
                        const float* __restrict__ be2,
                        float* __restrict__ out_nf,
                        unsigned short* __restrict__ xpb, float* __restrict__ btp,
                        float* __restrict__ aggw, int doXp) {
    int wid = (blockIdx.x * blockDim.x + threadIdx.x) >> 6;
    int lane = threadIdx.x & 63;
    int s0 = wid * 4;
    if (s0 >= NN) return;
    int nv = (NN - s0 < 4) ? (NN - s0) : 4;
    float nfv[4], hv[4], gr[4], gz[4], gn[4], hr[4], hz[4], hn[4];
    float bi0 = bih[lane], bi1 = bih[64 + lane], bi2 = bih[128 + lane];
    float bh0 = bhh[lane], bh1 = bhh[64 + lane], bh2 = bhh[128 + lane];
    #pragma unroll
    for (int i = 0; i < 4; i++) {
        int s = s0 + (i < nv ? i : nv - 1);
        float c = fmaxf(cnt[s], 1.f);
        nfv[i] = fmaxf(agg[(size_t)s * DD + lane] / c, 0.f);
        hv[i] = hid[(size_t)s * DD + lane];
        gr[i] = bi0; gz[i] = bi1; gn[i] = bi2;
        hr[i] = bh0; hz[i] = bh1; hn[i] = bh2;
    }
    for (int d = 0; d < 64; d++) {
        const float* wi = WihT + d * 192;
        const float* wh = WhhT + d * 192;
        float wi0 = wi[lane], wi1 = wi[64 + lane], wi2 = wi[128 + lane];
        float wh0 = wh[lane], wh1 = wh[64 + lane], wh2 = wh[128 + lane];
        #pragma unroll
        for (int i = 0; i < 4; i++) {
            float nd = __shfl(nfv[i], d, 64);
            float hd = __shfl(hv[i], d, 64);
            gr[i] = fmaf(nd, wi0, gr[i]);
            gz[i] = fmaf(nd, wi1, gz[i]);
            gn[i] = fmaf(nd, wi2, gn[i]);
            hr[i] = fmaf(hd, wh0, hr[i]);
            hz[i] = fmaf(hd, wh1, hz[i]);
            hn[i] = fmaf(hd, wh2, hn[i]);
        }
    }
    float newnf[4];
    #pragma unroll
    for (int i = 0; i < 4; i++) {
        float r = 1.f / (1.f + __expf(-(gr[i] + hr[i])));
        float z = 1.f / (1.f + __expf(-(gz[i] + hz[i])));
        float nn2 = tanhf(gn[i] + r * hn[i]);
        newnf[i] = (1.f - z) * nn2 + z * hv[i];
        if (i < nv) out_nf[(size_t)(s0 + i) * DD + lane] = newnf[i];
    }
    if (!doXp) return;
    float acc[4], bt[4];
    float blv = bl[lane];
    #pragma unroll
    for (int i = 0; i < 4; i++) { acc[i] = blv; bt[i] = 0.f; }
    for (int d = 0; d < 64; d++) {
        float wv = WlT[d * 64 + lane];
        #pragma unroll
        for (int i = 0; i < 4; i++)
            acc[i] = fmaf(__shfl(newnf[i], d, 64), wv, acc[i]);
    }
    for (int d = 0; d < 64; d++) {
        float bv = be2[d * 64 + lane];
        #pragma unroll
        for (int i = 0; i < 4; i++)
            bt[i] = fmaf(__shfl(acc[i], d, 64), bv, bt[i]);
    }
    #pragma unroll
    for (int i = 0; i < 4; i++) {
        if (i < nv) {
            xpb[(size_t)(s0 + i) * DD + lane] = f2b(acc[i]);
            btp[(size_t)(s0 + i) * DD + lane] = bt[i];
            aggw[(size_t)(s0 + i) * DD + lane] = 0.f;
        }
    }
}

extern "C" void kernel_launch(void* const* d_in, const int* in_sizes, int n_in,
                              void* d_out, int out_size, void* d_ws, size_t ws_size,
                              hipStream_t stream) {
    const float* x   = (const float*)d_in[0];
    const int*   ei  = (const int*)d_in[1];
    const float* ea  = (const float*)d_in[2];
    const float* Wp  = (const float*)d_in[3];
    const float* bp  = (const float*)d_in[4];
    const float* W1  = (const float*)d_in[5];
    const float* b1  = (const float*)d_in[6];
    const float* W2  = (const float*)d_in[7];
    const float* b2  = (const float*)d_in[8];
    const float* Wl  = (const float*)d_in[9];
    const float* bl  = (const float*)d_in[10];
    const float* Wih = (const float*)d_in[11];
    const float* Whh = (const float*)d_in[12];
    const float* bih = (const float*)d_in[13];
    const float* bhh = (const float*)d_in[14];
    const int* srcv = ei;
    const int* dstv = ei + NE;

    float* p = (float*)d_ws;
    size_t off = 0;
    auto alloc = [&](size_t n) { n = (n + 3) & ~(size_t)3; float* q = p + off; off += n; return q; };
    float* nf   = alloc((size_t)NN * DD);
    float* hid  = alloc((size_t)NN * DD);
    float* btp  = alloc((size_t)NN * DD);
    float* agg  = alloc((size_t)NN * DD);
    float* cnt  = alloc(NN);
    unsigned short* ehs = (unsigned short*)alloc((size_t)(NE + 16) * EH_ / 2);  // bf16
    float* WihT = alloc(192 * 64);
    float* WhhT = alloc(192 * 64);
    float* WlT  = alloc(64 * 64);
    int* hist   = (int*)alloc(NN);
    int* rowptr = (int*)alloc(NN + 1);
    int* cursor = (int*)alloc(NN);
    int* perm   = (int*)alloc(NE);
    int* dsts_s = (int*)alloc(NE);
    int* g_src  = (int*)alloc(GCAP);
    int* g_base = (int*)alloc(GCAP);
    int* g_cnt  = (int*)alloc(GCAP);
    int* d_ng   = (int*)alloc(4);
    unsigned short* Apk = (unsigned short*)alloc((size_t)(1 << 19) / 2);       // bf16, 1MB
    unsigned short* xpb = (unsigned short*)alloc((size_t)PADN * DD / 2);       // bf16

    // ---- one-time preprocessing ----
    k_zero<<<(NN + 255) / 256, 256, 0, stream>>>(cnt, NN);
    k_zero<<<(NN + 255) / 256, 256, 0, stream>>>((float*)hist, NN);
    k_zero<<<(GCAP + 255) / 256, 256, 0, stream>>>((float*)g_src, GCAP);
    k_zero<<<(GCAP + 255) / 256, 256, 0, stream>>>((float*)g_base, GCAP);
    k_zero<<<(GCAP + 255) / 256, 256, 0, stream>>>((float*)g_cnt, GCAP);
    k_proj<<<(NN + 3) / 4, 256, 0, stream>>>(x, Wp, bp, nf, hid);
    k_pA<<<(1 << 19) / 256, 256, 0, stream>>>(W2, Apk);
    k_tG<<<48, 256, 0, stream>>>(Wih, WihT);
    k_tG<<<48, 256, 0, stream>>>(Whh, WhhT);
    k_tr64<<<16, 256, 0, stream>>>(Wl, WlT);
    k_cnt<<<(NE + 255) / 256, 256, 0, stream>>>(dstv, cnt);
    k_hist<<<(NE + 255) / 256, 256, 0, stream>>>(srcv, hist);
    k_scan<<<1, 1024, 0, stream>>>(hist, rowptr, cursor);
    k_scatter<<<(NE + 255) / 256, 256, 0, stream>>>(srcv, dstv, cursor, perm, dsts_s);
    k_eh_s<<<(NE + 1) / 2, 256, 0, stream>>>(ea, W1, b1, perm, ehs);
    k_grp<<<1, 1024, 0, stream>>>(rowptr, g_src, g_base, g_cnt, d_ng);

    const int nw_quarter = (NN + 3) / 4;
    k_xp<<<(nw_quarter + 3) / 4, 256, 0, stream>>>(nf, WlT, bl, b2, xpb, btp, agg);
    for (int s = 0; s < NSTEPS; s++) {
        k_fv<<<GCAP / 16, 256, 0, stream>>>(xpb, Apk, g_src, g_base, g_cnt, d_ng,
                                            ehs, dsts_s, btp, agg);
        float* dest = (s == NSTEPS - 1) ? (float*)d_out : nf;
        k_gruxp<<<(nw_quarter + 3) / 4, 256, 0, stream>>>(agg, cnt, hid, WihT, WhhT,
                                                          bih, bhh, WlT, bl, b2,
                                                          dest, xpb, btp, agg,
                                                          (s < NSTEPS - 1) ? 1 : 0);
    }
}

// Round 9
// 810.752 us; speedup vs baseline: 1.3907x; 1.1614x over previous
//
#include <hip/hip_runtime.h>
#include <hip/hip_bf16.h>

#define NN 10000     // nodes
#define NE 100000    // edges
#define DD 64        // node_out_feats
#define EH_ 128      // edge_hidden_feats
#define NI_ 74       // node_in_feats
#define EI_ 12       // edge_in_feats
#define NSTEPS 6
#define PADN 10240
#define GCAP 16384   // max groups (ceil-sum bound 15625)

typedef short bf16x8 __attribute__((ext_vector_type(8)));
typedef float f32x4 __attribute__((ext_vector_type(4)));

static __device__ __forceinline__ unsigned short f2b(float f) {
    unsigned int u = __float_as_uint(f);
    u += 0x7fffu + ((u >> 16) & 1u);
    return (unsigned short)(u >> 16);
}

__global__ void k_zero(float* p, int n) {
    int i = blockIdx.x * blockDim.x + threadIdx.x;
    if (i < n) p[i] = 0.f;
}

// node_feats = relu(x @ W_proj^T + b_proj); hidden = node_feats. One wave per node.
__global__ void k_proj(const float* __restrict__ x, const float* __restrict__ Wp,
                       const float* __restrict__ bp, float* __restrict__ nf,
                       float* __restrict__ hid) {
    int w = (blockIdx.x * blockDim.x + threadIdx.x) >> 6;
    int lane = threadIdx.x & 63;
    if (w >= NN) return;
    const float* xr = x + (size_t)w * NI_;
    float x0 = xr[lane];
    float x1 = (lane < NI_ - 64) ? xr[64 + lane] : 0.f;
    float acc = bp[lane];
    const float* wr = Wp + (size_t)lane * NI_;
    #pragma unroll
    for (int i = 0; i < 64; i++) acc += __shfl(x0, i, 64) * wr[i];
    #pragma unroll
    for (int i = 0; i < NI_ - 64; i++) acc += __shfl(x1, i, 64) * wr[64 + i];
    acc = fmaxf(acc, 0.f);
    nf[(size_t)w * DD + lane] = acc;
    hid[(size_t)w * DD + lane] = acc;
}

__global__ void k_hist(const int* __restrict__ srcv, int* __restrict__ hist) {
    int e = blockIdx.x * blockDim.x + threadIdx.x;
    if (e < NE) atomicAdd(&hist[srcv[e]], 1);
}

// exclusive scan of hist -> rowptr[0..NN], cursor copy. Single block 1024 thr.
__global__ void k_scan(const int* __restrict__ hist, int* __restrict__ rowptr,
                       int* __restrict__ cursor) {
    __shared__ int part[1024];
    int t = threadIdx.x;
    const int PER = (NN + 1023) / 1024;
    int b0 = t * PER;
    int sum = 0;
    for (int i = 0; i < PER; i++) { int b = b0 + i; if (b < NN) sum += hist[b]; }
    part[t] = sum;
    __syncthreads();
    for (int off = 1; off < 1024; off <<= 1) {
        int v = (t >= off) ? part[t - off] : 0;
        __syncthreads();
        part[t] += v;
        __syncthreads();
    }
    int run = (t > 0) ? part[t - 1] : 0;
    for (int i = 0; i <= PER; i++) {
        int b = b0 + i;
        if (b <= NN) {
            rowptr[b] = run;
            if (b < NN) cursor[b] = run;
        }
        if (b < NN && i < PER) run += hist[b];
        if (i == PER) break;
    }
}

__global__ void k_scatter(const int* __restrict__ srcv, const int* __restrict__ dstv,
                          int* __restrict__ cursor, int* __restrict__ perm,
                          int* __restrict__ dsts_s) {
    int e = blockIdx.x * blockDim.x + threadIdx.x;
    if (e >= NE) return;
    int s = srcv[e];
    int pos = atomicAdd(&cursor[s], 1);
    perm[pos] = e;
    dsts_s[pos] = dstv[e];
}

// Build group list: group = (src, base, cnt<=16) over src-sorted edge ranges.
__global__ void k_grp(const int* __restrict__ rowptr, int* __restrict__ g_src,
                      int* __restrict__ g_base, int* __restrict__ g_cnt,
                      int* __restrict__ d_ng) {
    __shared__ int part[1024];
    int t = threadIdx.x;
    const int PER = (NN + 1023) / 1024;
    int b0 = t * PER;
    int cg = 0;
    for (int i = 0; i < PER; i++) {
        int b = b0 + i;
        if (b < NN) { int d = rowptr[b + 1] - rowptr[b]; cg += (d + 15) >> 4; }
    }
    part[t] = cg;
    __syncthreads();
    for (int off = 1; off < 1024; off <<= 1) {
        int v = (t >= off) ? part[t - off] : 0;
        __syncthreads();
        part[t] += v;
        __syncthreads();
    }
    int run = (t > 0) ? part[t - 1] : 0;
    for (int i = 0; i < PER; i++) {
        int b = b0 + i;
        if (b >= NN) break;
        int r0 = rowptr[b], r1 = rowptr[b + 1];
        for (int p = r0; p < r1; p += 16) {
            g_src[run] = b;
            g_base[run] = p;
            int c = r1 - p; if (c > 16) c = 16;
            g_cnt[run] = c;
            run++;
        }
    }
    if (t == 1023) *d_ng = run;
}

// eh (sorted order, bf16) = relu(edge_attr[perm[p]] @ W_e1^T + b_e1).
__global__ void k_eh_s(const float* __restrict__ ea, const float* __restrict__ W1,
                       const float* __restrict__ b1, const int* __restrict__ perm,
                       unsigned short* __restrict__ ehs) {
    __shared__ float s_ea[2][EI_];
    __shared__ float s_W[EH_ * EI_];
    int t = threadIdx.x;
    for (int i = t; i < EH_ * EI_; i += 256) s_W[i] = W1[i];
    int p0 = blockIdx.x * 2;
    if (t < 2 * EI_) {
        int pp = p0 + t / EI_;
        int ee = (pp < NE) ? perm[pp] : 0;
        s_ea[t / EI_][t % EI_] = (pp < NE) ? ea[(size_t)ee * EI_ + t % EI_] : 0.f;
    }
    __syncthreads();
    int le = t >> 7;
    int h = t & 127;
    int p = p0 + le;
    if (p >= NE) return;
    float acc = b1[h];
    #pragma unroll
    for (int i = 0; i < EI_; i++) acc += s_ea[le][i] * s_W[h * EI_ + i];
    ehs[(size_t)p * EH_ + h] = f2b(fmaxf(acc, 0.f));
}

// Pack W_e2 into bf16 MFMA A-fragment order for the fused kernel.
// Tile (ks,hB,f): idx = ((((ks*2+hB)*64+f)*2+frag)*4+g)*128 + n*8 + j,
// d=frag*32+g*8+j, h=ks*32+hB*16+n.
__global__ void k_pA(const float* __restrict__ W2, unsigned short* __restrict__ Apk) {
    int idx = blockIdx.x * 256 + threadIdx.x;
    if (idx >= (1 << 19)) return;
    int j = idx & 7;
    int n = (idx >> 3) & 15;
    int g = (idx >> 7) & 3;
    int frag = (idx >> 9) & 1;
    int f = (idx >> 10) & 63;
    int hB = (idx >> 16) & 1;
    int ks = idx >> 17;
    int d = frag * 32 + g * 8 + j;
    int h = ks * 32 + hB * 16 + n;
    Apk[idx] = f2b(W2[((size_t)(d * 64 + f)) * EH_ + h]);
}

__global__ void k_tG(const float* __restrict__ W, float* __restrict__ Wt) {
    int idx = blockIdx.x * 256 + threadIdx.x;
    if (idx >= 192 * 64) return;
    int j = idx / 64, d2 = idx % 64;
    Wt[d2 * 192 + j] = W[idx];
}

__global__ void k_tr64(const float* __restrict__ W, float* __restrict__ Wt) {
    int idx = blockIdx.x * 256 + threadIdx.x;
    if (idx >= 64 * 64) return;
    int r = idx >> 6, c = idx & 63;
    Wt[c * 64 + r] = W[idx];
}

__global__ void k_cnt(const int* __restrict__ dstv, float* __restrict__ cnt) {
    int e = blockIdx.x * blockDim.x + threadIdx.x;
    if (e < NE) atomicAdd(&cnt[dstv[e]], 1.0f);
}

// xp = nf @ W_lin^T + b_lin (-> bf16 xpb); btp = xp @ reshape(b_e2,64,64); agg = 0.
__global__ void k_xp(const float* __restrict__ nf, const float* __restrict__ WlT,
                     const float* __restrict__ bl, const float* __restrict__ be2,
                     unsigned short* __restrict__ xpb, float* __restrict__ btp,
                     float* __restrict__ agg) {
    int wid = (blockIdx.x * blockDim.x + threadIdx.x) >> 6;
    int lane = threadIdx.x & 63;
    int s0 = wid * 4;
    if (s0 >= NN) return;
    int nv = (NN - s0 < 4) ? (NN - s0) : 4;
    float nvv[4], acc[4], bt[4];
    float blv = bl[lane];
    #pragma unroll
    for (int i = 0; i < 4; i++) {
        int s = s0 + (i < nv ? i : nv - 1);
        nvv[i] = nf[(size_t)s * DD + lane];
        acc[i] = blv;
        bt[i] = 0.f;
    }
    for (int d = 0; d < 64; d++) {
        float wv = WlT[d * 64 + lane];
        #pragma unroll
        for (int i = 0; i < 4; i++)
            acc[i] = fmaf(__shfl(nvv[i], d, 64), wv, acc[i]);
    }
    for (int d = 0; d < 64; d++) {
        float bv = be2[d * 64 + lane];
        #pragma unroll
        for (int i = 0; i < 4; i++)
            bt[i] = fmaf(__shfl(acc[i], d, 64), bv, bt[i]);
    }
    #pragma unroll
    for (int i = 0; i < 4; i++) {
        if (i < nv) {
            xpb[(size_t)(s0 + i) * DD + lane] = f2b(acc[i]);
            btp[(size_t)(s0 + i) * DD + lane] = bt[i];
            agg[(size_t)(s0 + i) * DD + lane] = 0.f;
        }
    }
}

// Fused V-GEMM + edge MFMA. Block = 8 waves (512 thr), 16 groups.
// Per ks (32 h): phase A computes V-slice (16 nodes x 32h x 64f) into XOR-swizzled
// LDS via MFMA (each wave handles 8 f-columns); phase B: each wave serves 2 groups,
// ds_read_b128 B-frags + edge MFMA (K=32) accumulating across ks.
__global__ __launch_bounds__(512, 4) void k_fv(
        const unsigned short* __restrict__ xpb,
        const unsigned short* __restrict__ Apk,
        const int* __restrict__ g_src, const int* __restrict__ g_base,
        const int* __restrict__ g_cnt, const int* __restrict__ d_ng,
        const unsigned short* __restrict__ ehs, const int* __restrict__ dsts,
        const float* __restrict__ btp, float* __restrict__ agg) {
    __shared__ unsigned char lds[65536];
    int ng = *d_ng;
    int nb = blockIdx.x * 16;
    if (nb >= ng) return;
    int tid = threadIdx.x;
    int w = tid >> 6, lane = tid & 63;      // w in [0,8)
    int g = lane >> 4, n = lane & 15;

    // xp B-fragments for the block's 16 slots (col n = slot)
    int srcn = g_src[nb + n];
    const unsigned short* xr = xpb + (size_t)srcn * DD + g * 8;
    bf16x8 xb0 = *(const bf16x8*)xr;
    bf16x8 xb1 = *(const bf16x8*)(xr + 32);

    // per-wave group metadata (2 groups per wave, uniform)
    int sq[2], bq[2], cq[2];
    #pragma unroll
    for (int q = 0; q < 2; q++) {
        int gi = nb + w * 2 + q;
        sq[q] = g_src[gi]; bq[q] = g_base[gi]; cq[q] = g_cnt[gi];
    }

    f32x4 acc[2][4];
    #pragma unroll
    for (int q = 0; q < 2; q++)
        #pragma unroll
        for (int nt = 0; nt < 4; nt++) {
            f32x4 z = {0.f, 0.f, 0.f, 0.f};
            acc[q][nt] = z;
        }

    for (int ks = 0; ks < 4; ks++) {
        if (ks) __syncthreads();
        // ---- phase A: V slice -> LDS (wave w: f in [w*8, w*8+8)) ----
        #pragma unroll
        for (int hB = 0; hB < 2; hB++) {
            int ho = hB * 2 + (g >> 1);
            int hq0 = (g & 1) * 4;
            int abase = (n << 12) | (ho << 4) | (hq0 << 1);
            const unsigned short* apks =
                Apk + (size_t)((ks * 2 + hB) * 64 + (w << 3)) * 1024 + g * 128 + n * 8;
            #pragma unroll
            for (int fi = 0; fi < 8; fi++) {
                int f = (w << 3) + fi;
                const unsigned short* ap = apks + fi * 1024;
                bf16x8 A0 = *(const bf16x8*)ap;
                bf16x8 A1 = *(const bf16x8*)(ap + 512);
                f32x4 d = {0.f, 0.f, 0.f, 0.f};
                d = __builtin_amdgcn_mfma_f32_16x16x32_bf16(A0, xb0, d, 0, 0, 0);
                d = __builtin_amdgcn_mfma_f32_16x16x32_bf16(A1, xb1, d, 0, 0, 0);
                unsigned int lo = (unsigned)f2b(d[0]) | ((unsigned)f2b(d[1]) << 16);
                unsigned int hi = (unsigned)f2b(d[2]) | ((unsigned)f2b(d[3]) << 16);
                int addr = abase | (f << 6);
                addr ^= ((n ^ f) & 7) << 4;
                *(unsigned long long*)(lds + addr) =
                    (unsigned long long)lo | ((unsigned long long)hi << 32);
            }
        }
        // prefetch eh A-frags for this ks (no LDS dependency)
        bf16x8 aeh[2];
        #pragma unroll
        for (int q = 0; q < 2; q++)
            aeh[q] = *(const bf16x8*)(ehs + (size_t)(bq[q] + n) * EH_ + ks * 32 + g * 8);
        __syncthreads();
        // ---- phase B: edge MFMA from LDS ----
        bf16x8 Bf[2][4];
        #pragma unroll
        for (int q = 0; q < 2; q++) {
            int sl = w * 2 + q;
            #pragma unroll
            for (int nt = 0; nt < 4; nt++) {
                int f = nt * 16 + n;
                int addr = (sl << 12) | (f << 6) | (g << 4);
                addr ^= ((sl ^ f) & 7) << 4;
                Bf[q][nt] = *(const bf16x8*)(lds + addr);
            }
        }
        #pragma unroll
        for (int q = 0; q < 2; q++)
            #pragma unroll
            for (int nt = 0; nt < 4; nt++)
                acc[q][nt] = __builtin_amdgcn_mfma_f32_16x16x32_bf16(aeh[q], Bf[q][nt],
                                                                     acc[q][nt], 0, 0, 0);
    }
    // ---- epilogue: atomics ----
    #pragma unroll
    for (int q = 0; q < 2; q++) {
        if (cq[q] == 0) continue;
        #pragma unroll
        for (int nt = 0; nt < 4; nt++) {
            float btv = btp[(size_t)sq[q] * DD + nt * 16 + n];
            #pragma unroll
            for (int rg = 0; rg < 4; rg++) {
                int m = g * 4 + rg;
                if (m < cq[q]) {
                    int dn = dsts[bq[q] + m];
                    atomicAdd(&agg[(size_t)dn * DD + nt * 16 + n], acc[q][nt][rg] + btv);
                }
            }
        }
    }
}

// Fused GRU + next-step xp. 4 nodes per wave.
__global__ void k_gruxp(const float* __restrict__ agg, const float* __restrict__ cnt,
                        const float* __restrict__ hid,
                        const float* __restrict__ WihT, const float* __restrict__ WhhT,
                        const float* __restrict__ bih, const float* __restrict__ bhh,
                        const float* __restrict__ WlT, const float* __restrict__ bl,
                        const float* __restrict__ be2,
                        float* __restrict__ out_nf,
                        unsigned short* __restrict__ xpb, float* __restrict__ btp,
                        float* __restrict__ aggw, int doXp) {
    int wid = (blockIdx.x * blockDim.x + threadIdx.x) >> 6;
    int lane = threadIdx.x & 63;
    int s0 = wid * 4;
    if (s0 >= NN) return;
    int nv = (NN - s0 < 4) ? (NN - s0) : 4;
    float nfv[4], hv[4], gr[4], gz[4], gn[4], hr[4], hz[4], hn[4];
    float bi0 = bih[lane], bi1 = bih[64 + lane], bi2 = bih[128 + lane];
    float bh0 = bhh[lane], bh1 = bhh[64 + lane], bh2 = bhh[128 + lane];
    #pragma unroll
    for (int i = 0; i < 4; i++) {
        int s = s0 + (i < nv ? i : nv - 1);
        float c = fmaxf(cnt[s], 1.f);
        nfv[i] = fmaxf(agg[(size_t)s * DD + lane] / c, 0.f);
        hv[i] = hid[(size_t)s * DD + lane];
        gr[i] = bi0; gz[i] = bi1; gn[i] = bi2;
        hr[i] = bh0; hz[i] = bh1; hn[i] = bh2;
    }
    for (int d = 0; d < 64; d++) {
        const float* wi = WihT + d * 192;
        const float* wh = WhhT + d * 192;
        float wi0 = wi[lane], wi1 = wi[64 + lane], wi2 = wi[128 + lane];
        float wh0 = wh[lane], wh1 = wh[64 + lane], wh2 = wh[128 + lane];
        #pragma unroll
        for (int i = 0; i < 4; i++) {
            float nd = __shfl(nfv[i], d, 64);
            float hd = __shfl(hv[i], d, 64);
            gr[i] = fmaf(nd, wi0, gr[i]);
            gz[i] = fmaf(nd, wi1, gz[i]);
            gn[i] = fmaf(nd, wi2, gn[i]);
            hr[i] = fmaf(hd, wh0, hr[i]);
            hz[i] = fmaf(hd, wh1, hz[i]);
            hn[i] = fmaf(hd, wh2, hn[i]);
        }
    }
    float newnf[4];
    #pragma unroll
    for (int i = 0; i < 4; i++) {
        float r = 1.f / (1.f + __expf(-(gr[i] + hr[i])));
        float z = 1.f / (1.f + __expf(-(gz[i] + hz[i])));
        float nn2 = tanhf(gn[i] + r * hn[i]);
        newnf[i] = (1.f - z) * nn2 + z * hv[i];
        if (i < nv) out_nf[(size_t)(s0 + i) * DD + lane] = newnf[i];
    }
    if (!doXp) return;
    float acc[4], bt[4];
    float blv = bl[lane];
    #pragma unroll
    for (int i = 0; i < 4; i++) { acc[i] = blv; bt[i] = 0.f; }
    for (int d = 0; d < 64; d++) {
        float wv = WlT[d * 64 + lane];
        #pragma unroll
        for (int i = 0; i < 4; i++)
            acc[i] = fmaf(__shfl(newnf[i], d, 64), wv, acc[i]);
    }
    for (int d = 0; d < 64; d++) {
        float bv = be2[d * 64 + lane];
        #pragma unroll
        for (int i = 0; i < 4; i++)
            bt[i] = fmaf(__shfl(acc[i], d, 64), bv, bt[i]);
    }
    #pragma unroll
    for (int i = 0; i < 4; i++) {
        if (i < nv) {
            xpb[(size_t)(s0 + i) * DD + lane] = f2b(acc[i]);
            btp[(size_t)(s0 + i) * DD + lane] = bt[i];
            aggw[(size_t)(s0 + i) * DD + lane] = 0.f;
        }
    }
}

extern "C" void kernel_launch(void* const* d_in, const int* in_sizes, int n_in,
                              void* d_out, int out_size, void* d_ws, size_t ws_size,
                              hipStream_t stream) {
    const float* x   = (const float*)d_in[0];
    const int*   ei  = (const int*)d_in[1];
    const float* ea  = (const float*)d_in[2];
    const float* Wp  = (const float*)d_in[3];
    const float* bp  = (const float*)d_in[4];
    const float* W1  = (const float*)d_in[5];
    const float* b1  = (const float*)d_in[6];
    const float* W2  = (const float*)d_in[7];
    const float* b2  = (const float*)d_in[8];
    const float* Wl  = (const float*)d_in[9];
    const float* bl  = (const float*)d_in[10];
    const float* Wih = (const float*)d_in[11];
    const float* Whh = (const float*)d_in[12];
    const float* bih = (const float*)d_in[13];
    const float* bhh = (const float*)d_in[14];
    const int* srcv = ei;
    const int* dstv = ei + NE;

    float* p = (float*)d_ws;
    size_t off = 0;
    auto alloc = [&](size_t n) { n = (n + 3) & ~(size_t)3; float* q = p + off; off += n; return q; };
    float* nf   = alloc((size_t)NN * DD);
    float* hid  = alloc((size_t)NN * DD);
    float* btp  = alloc((size_t)NN * DD);
    float* agg  = alloc((size_t)NN * DD);
    float* cnt  = alloc(NN);
    unsigned short* ehs = (unsigned short*)alloc((size_t)(NE + 16) * EH_ / 2);  // bf16
    float* WihT = alloc(192 * 64);
    float* WhhT = alloc(192 * 64);
    float* WlT  = alloc(64 * 64);
    int* hist   = (int*)alloc(NN);
    int* rowptr = (int*)alloc(NN + 1);
    int* cursor = (int*)alloc(NN);
    int* perm   = (int*)alloc(NE);
    int* dsts_s = (int*)alloc(NE);
    int* g_src  = (int*)alloc(GCAP);
    int* g_base = (int*)alloc(GCAP);
    int* g_cnt  = (int*)alloc(GCAP);
    int* d_ng   = (int*)alloc(4);
    unsigned short* Apk = (unsigned short*)alloc((size_t)(1 << 19) / 2);       // bf16, 1MB
    unsigned short* xpb = (unsigned short*)alloc((size_t)PADN * DD / 2);       // bf16

    // ---- one-time preprocessing ----
    k_zero<<<(NN + 255) / 256, 256, 0, stream>>>(cnt, NN);
    k_zero<<<(NN + 255) / 256, 256, 0, stream>>>((float*)hist, NN);
    k_zero<<<(GCAP + 255) / 256, 256, 0, stream>>>((float*)g_src, GCAP);
    k_zero<<<(GCAP + 255) / 256, 256, 0, stream>>>((float*)g_base, GCAP);
    k_zero<<<(GCAP + 255) / 256, 256, 0, stream>>>((float*)g_cnt, GCAP);
    k_proj<<<(NN + 3) / 4, 256, 0, stream>>>(x, Wp, bp, nf, hid);
    k_pA<<<(1 << 19) / 256, 256, 0, stream>>>(W2, Apk);
    k_tG<<<48, 256, 0, stream>>>(Wih, WihT);
    k_tG<<<48, 256, 0, stream>>>(Whh, WhhT);
    k_tr64<<<16, 256, 0, stream>>>(Wl, WlT);
    k_cnt<<<(NE + 255) / 256, 256, 0, stream>>>(dstv, cnt);
    k_hist<<<(NE + 255) / 256, 256, 0, stream>>>(srcv, hist);
    k_scan<<<1, 1024, 0, stream>>>(hist, rowptr, cursor);
    k_scatter<<<(NE + 255) / 256, 256, 0, stream>>>(srcv, dstv, cursor, perm, dsts_s);
    k_eh_s<<<(NE + 1) / 2, 256, 0, stream>>>(ea, W1, b1, perm, ehs);
    k_grp<<<1, 1024, 0, stream>>>(rowptr, g_src, g_base, g_cnt, d_ng);

    const int nw_quarter = (NN + 3) / 4;
    k_xp<<<(nw_quarter + 3) / 4, 256, 0, stream>>>(nf, WlT, bl, b2, xpb, btp, agg);
    for (int s = 0; s < NSTEPS; s++) {
        k_fv<<<GCAP / 16, 512, 0, stream>>>(xpb, Apk, g_src, g_base, g_cnt, d_ng,
                                            ehs, dsts_s, btp, agg);
        float* dest = (s == NSTEPS - 1) ? (float*)d_out : nf;
        k_gruxp<<<(nw_quarter + 3) / 4, 256, 0, stream>>>(agg, cnt, hid, WihT, WhhT,
                                                          bih, bhh, WlT, bl, b2,
                                                          dest, xpb, btp, agg,
                                                          (s < NSTEPS - 1) ? 1 : 0);
    }
}

// Round 10
// 729.366 us; speedup vs baseline: 1.5459x; 1.1116x over previous
//
#include <hip/hip_runtime.h>
#include <hip/hip_bf16.h>

#define NN 10000     // nodes
#define NE 100000    // edges
#define DD 64        // node_out_feats
#define EH_ 128      // edge_hidden_feats
#define NI_ 74       // node_in_feats
#define EI_ 12       // edge_in_feats
#define NSTEPS 6
#define PADN 10240
#define GCAP 16384   // max groups (ceil-sum bound 15625)

typedef short bf16x8 __attribute__((ext_vector_type(8)));
typedef float f32x4 __attribute__((ext_vector_type(4)));

static __device__ __forceinline__ unsigned short f2b(float f) {
    unsigned int u = __float_as_uint(f);
    u += 0x7fffu + ((u >> 16) & 1u);
    return (unsigned short)(u >> 16);
}

__global__ void k_zero(float* p, int n) {
    int i = blockIdx.x * blockDim.x + threadIdx.x;
    if (i < n) p[i] = 0.f;
}

// node_feats = relu(x @ W_proj^T + b_proj); hidden = node_feats. One wave per node.
__global__ void k_proj(const float* __restrict__ x, const float* __restrict__ Wp,
                       const float* __restrict__ bp, float* __restrict__ nf,
                       float* __restrict__ hid) {
    int w = (blockIdx.x * blockDim.x + threadIdx.x) >> 6;
    int lane = threadIdx.x & 63;
    if (w >= NN) return;
    const float* xr = x + (size_t)w * NI_;
    float x0 = xr[lane];
    float x1 = (lane < NI_ - 64) ? xr[64 + lane] : 0.f;
    float acc = bp[lane];
    const float* wr = Wp + (size_t)lane * NI_;
    #pragma unroll
    for (int i = 0; i < 64; i++) acc += __shfl(x0, i, 64) * wr[i];
    #pragma unroll
    for (int i = 0; i < NI_ - 64; i++) acc += __shfl(x1, i, 64) * wr[64 + i];
    acc = fmaxf(acc, 0.f);
    nf[(size_t)w * DD + lane] = acc;
    hid[(size_t)w * DD + lane] = acc;
}

__global__ void k_hist(const int* __restrict__ srcv, int* __restrict__ hist) {
    int e = blockIdx.x * blockDim.x + threadIdx.x;
    if (e < NE) atomicAdd(&hist[srcv[e]], 1);
}

// exclusive scan of hist -> rowptr[0..NN], cursor copy. Single block 1024 thr.
__global__ void k_scan(const int* __restrict__ hist, int* __restrict__ rowptr,
                       int* __restrict__ cursor) {
    __shared__ int part[1024];
    int t = threadIdx.x;
    const int PER = (NN + 1023) / 1024;
    int b0 = t * PER;
    int sum = 0;
    for (int i = 0; i < PER; i++) { int b = b0 + i; if (b < NN) sum += hist[b]; }
    part[t] = sum;
    __syncthreads();
    for (int off = 1; off < 1024; off <<= 1) {
        int v = (t >= off) ? part[t - off] : 0;
        __syncthreads();
        part[t] += v;
        __syncthreads();
    }
    int run = (t > 0) ? part[t - 1] : 0;
    for (int i = 0; i <= PER; i++) {
        int b = b0 + i;
        if (b <= NN) {
            rowptr[b] = run;
            if (b < NN) cursor[b] = run;
        }
        if (b < NN && i < PER) run += hist[b];
        if (i == PER) break;
    }
}

__global__ void k_scatter(const int* __restrict__ srcv, const int* __restrict__ dstv,
                          int* __restrict__ cursor, int* __restrict__ perm,
                          int* __restrict__ dsts_s) {
    int e = blockIdx.x * blockDim.x + threadIdx.x;
    if (e >= NE) return;
    int s = srcv[e];
    int pos = atomicAdd(&cursor[s], 1);
    perm[pos] = e;
    dsts_s[pos] = dstv[e];
}

// Build group list: group = (src, base, cnt<=16) over src-sorted edge ranges.
__global__ void k_grp(const int* __restrict__ rowptr, int* __restrict__ g_src,
                      int* __restrict__ g_base, int* __restrict__ g_cnt,
                      int* __restrict__ d_ng) {
    __shared__ int part[1024];
    int t = threadIdx.x;
    const int PER = (NN + 1023) / 1024;
    int b0 = t * PER;
    int cg = 0;
    for (int i = 0; i < PER; i++) {
        int b = b0 + i;
        if (b < NN) { int d = rowptr[b + 1] - rowptr[b]; cg += (d + 15) >> 4; }
    }
    part[t] = cg;
    __syncthreads();
    for (int off = 1; off < 1024; off <<= 1) {
        int v = (t >= off) ? part[t - off] : 0;
        __syncthreads();
        part[t] += v;
        __syncthreads();
    }
    int run = (t > 0) ? part[t - 1] : 0;
    for (int i = 0; i < PER; i++) {
        int b = b0 + i;
        if (b >= NN) break;
        int r0 = rowptr[b], r1 = rowptr[b + 1];
        for (int p = r0; p < r1; p += 16) {
            g_src[run] = b;
            g_base[run] = p;
            int c = r1 - p; if (c > 16) c = 16;
            g_cnt[run] = c;
            run++;
        }
    }
    if (t == 1023) *d_ng = run;
}

// eh (sorted order, bf16) = relu(edge_attr[perm[p]] @ W_e1^T + b_e1).
__global__ void k_eh_s(const float* __restrict__ ea, const float* __restrict__ W1,
                       const float* __restrict__ b1, const int* __restrict__ perm,
                       unsigned short* __restrict__ ehs) {
    __shared__ float s_ea[2][EI_];
    __shared__ float s_W[EH_ * EI_];
    int t = threadIdx.x;
    for (int i = t; i < EH_ * EI_; i += 256) s_W[i] = W1[i];
    int p0 = blockIdx.x * 2;
    if (t < 2 * EI_) {
        int pp = p0 + t / EI_;
        int ee = (pp < NE) ? perm[pp] : 0;
        s_ea[t / EI_][t % EI_] = (pp < NE) ? ea[(size_t)ee * EI_ + t % EI_] : 0.f;
    }
    __syncthreads();
    int le = t >> 7;
    int h = t & 127;
    int p = p0 + le;
    if (p >= NE) return;
    float acc = b1[h];
    #pragma unroll
    for (int i = 0; i < EI_; i++) acc += s_ea[le][i] * s_W[h * EI_ + i];
    ehs[(size_t)p * EH_ + h] = f2b(fmaxf(acc, 0.f));
}

// Pack W_e2 into bf16 MFMA A-fragment order for the fused kernel.
// Tile (ks,hB,f): idx = ((((ks*2+hB)*64+f)*2+frag)*4+g)*128 + n*8 + j,
// d=frag*32+g*8+j, h=ks*32+hB*16+n.
__global__ void k_pA(const float* __restrict__ W2, unsigned short* __restrict__ Apk) {
    int idx = blockIdx.x * 256 + threadIdx.x;
    if (idx >= (1 << 19)) return;
    int j = idx & 7;
    int n = (idx >> 3) & 15;
    int g = (idx >> 7) & 3;
    int frag = (idx >> 9) & 1;
    int f = (idx >> 10) & 63;
    int hB = (idx >> 16) & 1;
    int ks = idx >> 17;
    int d = frag * 32 + g * 8 + j;
    int h = ks * 32 + hB * 16 + n;
    Apk[idx] = f2b(W2[((size_t)(d * 64 + f)) * EH_ + h]);
}

__global__ void k_tG(const float* __restrict__ W, float* __restrict__ Wt) {
    int idx = blockIdx.x * 256 + threadIdx.x;
    if (idx >= 192 * 64) return;
    int j = idx / 64, d2 = idx % 64;
    Wt[d2 * 192 + j] = W[idx];
}

__global__ void k_tr64(const float* __restrict__ W, float* __restrict__ Wt) {
    int idx = blockIdx.x * 256 + threadIdx.x;
    if (idx >= 64 * 64) return;
    int r = idx >> 6, c = idx & 63;
    Wt[c * 64 + r] = W[idx];
}

__global__ void k_cnt(const int* __restrict__ dstv, float* __restrict__ cnt) {
    int e = blockIdx.x * blockDim.x + threadIdx.x;
    if (e < NE) atomicAdd(&cnt[dstv[e]], 1.0f);
}

// xp = nf @ W_lin^T + b_lin (-> bf16 xpb); btp = xp @ reshape(b_e2,64,64); agg = 0.
__global__ void k_xp(const float* __restrict__ nf, const float* __restrict__ WlT,
                     const float* __restrict__ bl, const float* __restrict__ be2,
                     unsigned short* __restrict__ xpb, float* __restrict__ btp,
                     float* __restrict__ agg) {
    int wid = (blockIdx.x * blockDim.x + threadIdx.x) >> 6;
    int lane = threadIdx.x & 63;
    int s0 = wid * 4;
    if (s0 >= NN) return;
    int nv = (NN - s0 < 4) ? (NN - s0) : 4;
    float nvv[4], acc[4], bt[4];
    float blv = bl[lane];
    #pragma unroll
    for (int i = 0; i < 4; i++) {
        int s = s0 + (i < nv ? i : nv - 1);
        nvv[i] = nf[(size_t)s * DD + lane];
        acc[i] = blv;
        bt[i] = 0.f;
    }
    for (int d = 0; d < 64; d++) {
        float wv = WlT[d * 64 + lane];
        #pragma unroll
        for (int i = 0; i < 4; i++)
            acc[i] = fmaf(__shfl(nvv[i], d, 64), wv, acc[i]);
    }
    for (int d = 0; d < 64; d++) {
        float bv = be2[d * 64 + lane];
        #pragma unroll
        for (int i = 0; i < 4; i++)
            bt[i] = fmaf(__shfl(acc[i], d, 64), bv, bt[i]);
    }
    #pragma unroll
    for (int i = 0; i < 4; i++) {
        if (i < nv) {
            xpb[(size_t)(s0 + i) * DD + lane] = f2b(acc[i]);
            btp[(size_t)(s0 + i) * DD + lane] = bt[i];
            agg[(size_t)(s0 + i) * DD + lane] = 0.f;
        }
    }
}

// Fused V-GEMM + edge MFMA. Block = 16 waves (1024 thr), 16 groups.
// Per ks (32 h): phase A computes V-slice (16 nodes x 32h x 64f) into XOR-swizzled
// LDS via MFMA (each wave handles 4 f-columns); phase B: each wave serves 1 group.
// __launch_bounds__(1024,8) forces <=64 VGPR -> 2 blocks/CU = 32 waves/CU.
__global__ __launch_bounds__(1024, 8) void k_fv(
        const unsigned short* __restrict__ xpb,
        const unsigned short* __restrict__ Apk,
        const int* __restrict__ g_src, const int* __restrict__ g_base,
        const int* __restrict__ g_cnt, const int* __restrict__ d_ng,
        const unsigned short* __restrict__ ehs, const int* __restrict__ dsts,
        const float* __restrict__ btp, float* __restrict__ agg) {
    __shared__ unsigned char lds[65536];
    int ng = *d_ng;
    int nb = blockIdx.x * 16;
    if (nb >= ng) return;
    int tid = threadIdx.x;
    int w = tid >> 6, lane = tid & 63;      // w in [0,16)
    int g = lane >> 4, n = lane & 15;

    // xp B-fragments for the block's 16 slots (col n = slot)
    int srcn = g_src[nb + n];
    const unsigned short* xr = xpb + (size_t)srcn * DD + g * 8;
    bf16x8 xb0 = *(const bf16x8*)xr;
    bf16x8 xb1 = *(const bf16x8*)(xr + 32);

    // this wave's group metadata (uniform)
    int gi = nb + w;
    int sq = g_src[gi], bq = g_base[gi], cq = g_cnt[gi];

    f32x4 acc[4];
    #pragma unroll
    for (int nt = 0; nt < 4; nt++) {
        f32x4 z = {0.f, 0.f, 0.f, 0.f};
        acc[nt] = z;
    }

    for (int ks = 0; ks < 4; ks++) {
        if (ks) __syncthreads();
        // ---- phase A: V slice -> LDS (wave w: f in [w*4, w*4+4)) ----
        #pragma unroll
        for (int hB = 0; hB < 2; hB++) {
            int ho = hB * 2 + (g >> 1);
            int hq0 = (g & 1) * 4;
            int abase = (n << 12) | (ho << 4) | (hq0 << 1);
            const unsigned short* apks =
                Apk + (size_t)((ks * 2 + hB) * 64 + (w << 2)) * 1024 + g * 128 + n * 8;
            #pragma unroll
            for (int fi = 0; fi < 4; fi++) {
                int f = (w << 2) + fi;
                const unsigned short* ap = apks + fi * 1024;
                bf16x8 A0 = *(const bf16x8*)ap;
                bf16x8 A1 = *(const bf16x8*)(ap + 512);
                f32x4 d = {0.f, 0.f, 0.f, 0.f};
                d = __builtin_amdgcn_mfma_f32_16x16x32_bf16(A0, xb0, d, 0, 0, 0);
                d = __builtin_amdgcn_mfma_f32_16x16x32_bf16(A1, xb1, d, 0, 0, 0);
                unsigned int lo = (unsigned)f2b(d[0]) | ((unsigned)f2b(d[1]) << 16);
                unsigned int hi = (unsigned)f2b(d[2]) | ((unsigned)f2b(d[3]) << 16);
                int addr = abase | (f << 6);
                addr ^= ((n ^ f) & 7) << 4;
                *(unsigned long long*)(lds + addr) =
                    (unsigned long long)lo | ((unsigned long long)hi << 32);
            }
        }
        // prefetch eh A-frag for this ks (no LDS dependency)
        bf16x8 aeh = *(const bf16x8*)(ehs + (size_t)(bq + n) * EH_ + ks * 32 + g * 8);
        __syncthreads();
        // ---- phase B: edge MFMA from LDS (1 group per wave, sl = w) ----
        bf16x8 Bf[4];
        #pragma unroll
        for (int nt = 0; nt < 4; nt++) {
            int f = nt * 16 + n;
            int addr = (w << 12) | (f << 6) | (g << 4);
            addr ^= ((w ^ f) & 7) << 4;
            Bf[nt] = *(const bf16x8*)(lds + addr);
        }
        #pragma unroll
        for (int nt = 0; nt < 4; nt++)
            acc[nt] = __builtin_amdgcn_mfma_f32_16x16x32_bf16(aeh, Bf[nt], acc[nt], 0, 0, 0);
    }
    // ---- epilogue: atomics ----
    if (cq == 0) return;
    #pragma unroll
    for (int nt = 0; nt < 4; nt++) {
        float btv = btp[(size_t)sq * DD + nt * 16 + n];
        #pragma unroll
        for (int rg = 0; rg < 4; rg++) {
            int m = g * 4 + rg;
            if (m < cq) {
                int dn = dsts[bq + m];
                atomicAdd(&agg[(size_t)dn * DD + nt * 16 + n], acc[nt][rg] + btv);
            }
        }
    }
}

// Fused GRU + next-step xp. 4 nodes per wave.
__global__ void k_gruxp(const float* __restrict__ agg, const float* __restrict__ cnt,
                        const float* __restrict__ hid,
                        const float* __restrict__ WihT, const float* __restrict__ WhhT,
                        const float* __restrict__ bih, const float* __restrict__ bhh,
                        const float* __restrict__ WlT, const float* __restrict__ bl,
                        const float* __restrict__ be2,
                        float* __restrict__ out_nf,
                        unsigned short* __restrict__ xpb, float* __restrict__ btp,
                        float* __restrict__ aggw, int doXp) {
    int wid = (blockIdx.x * blockDim.x + threadIdx.x) >> 6;
    int lane = threadIdx.x & 63;
    int s0 = wid * 4;
    if (s0 >= NN) return;
    int nv = (NN - s0 < 4) ? (NN - s0) : 4;
    float nfv[4], hv[4], gr[4], gz[4], gn[4], hr[4], hz[4], hn[4];
    float bi0 = bih[lane], bi1 = bih[64 + lane], bi2 = bih[128 + lane];
    float bh0 = bhh[lane], bh1 = bhh[64 + lane], bh2 = bhh[128 + lane];
    #pragma unroll
    for (int i = 0; i < 4; i++) {
        int s = s0 + (i < nv ? i : nv - 1);
        float c = fmaxf(cnt[s], 1.f);
        nfv[i] = fmaxf(agg[(size_t)s * DD + lane] / c, 0.f);
        hv[i] = hid[(size_t)s * DD + lane];
        gr[i] = bi0; gz[i] = bi1; gn[i] = bi2;
        hr[i] = bh0; hz[i] = bh1; hn[i] = bh2;
    }
    for (int d = 0; d < 64; d++) {
        const float* wi = WihT + d * 192;
        const float* wh = WhhT + d * 192;
        float wi0 = wi[lane], wi1 = wi[64 + lane], wi2 = wi[128 + lane];
        float wh0 = wh[lane], wh1 = wh[64 + lane], wh2 = wh[128 + lane];
        #pragma unroll
        for (int i = 0; i < 4; i++) {
            float nd = __shfl(nfv[i], d, 64);
            float hd = __shfl(hv[i], d, 64);
            gr[i] = fmaf(nd, wi0, gr[i]);
            gz[i] = fmaf(nd, wi1, gz[i]);
            gn[i] = fmaf(nd, wi2, gn[i]);
            hr[i] = fmaf(hd, wh0, hr[i]);
            hz[i] = fmaf(hd, wh1, hz[i]);
            hn[i] = fmaf(hd, wh2, hn[i]);
        }
    }
    float newnf[4];
    #pragma unroll
    for (int i = 0; i < 4; i++) {
        float r = 1.f / (1.f + __expf(-(gr[i] + hr[i])));
        float z = 1.f / (1.f + __expf(-(gz[i] + hz[i])));
        float nn2 = tanhf(gn[i] + r * hn[i]);
        newnf[i] = (1.f - z) * nn2 + z * hv[i];
        if (i < nv) out_nf[(size_t)(s0 + i) * DD + lane] = newnf[i];
    }
    if (!doXp) return;
    float acc[4], bt[4];
    float blv = bl[lane];
    #pragma unroll
    for (int i = 0; i < 4; i++) { acc[i] = blv; bt[i] = 0.f; }
    for (int d = 0; d < 64; d++) {
        float wv = WlT[d * 64 + lane];
        #pragma unroll
        for (int i = 0; i < 4; i++)
            acc[i] = fmaf(__shfl(newnf[i], d, 64), wv, acc[i]);
    }
    for (int d = 0; d < 64; d++) {
        float bv = be2[d * 64 + lane];
        #pragma unroll
        for (int i = 0; i < 4; i++)
            bt[i] = fmaf(__shfl(acc[i], d, 64), bv, bt[i]);
    }
    #pragma unroll
    for (int i = 0; i < 4; i++) {
        if (i < nv) {
            xpb[(size_t)(s0 + i) * DD + lane] = f2b(acc[i]);
            btp[(size_t)(s0 + i) * DD + lane] = bt[i];
            aggw[(size_t)(s0 + i) * DD + lane] = 0.f;
        }
    }
}

extern "C" void kernel_launch(void* const* d_in, const int* in_sizes, int n_in,
                              void* d_out, int out_size, void* d_ws, size_t ws_size,
                              hipStream_t stream) {
    const float* x   = (const float*)d_in[0];
    const int*   ei  = (const int*)d_in[1];
    const float* ea  = (const float*)d_in[2];
    const float* Wp  = (const float*)d_in[3];
    const float* bp  = (const float*)d_in[4];
    const float* W1  = (const float*)d_in[5];
    const float* b1  = (const float*)d_in[6];
    const float* W2  = (const float*)d_in[7];
    const float* b2  = (const float*)d_in[8];
    const float* Wl  = (const float*)d_in[9];
    const float* bl  = (const float*)d_in[10];
    const float* Wih = (const float*)d_in[11];
    const float* Whh = (const float*)d_in[12];
    const float* bih = (const float*)d_in[13];
    const float* bhh = (const float*)d_in[14];
    const int* srcv = ei;
    const int* dstv = ei + NE;

    float* p = (float*)d_ws;
    size_t off = 0;
    auto alloc = [&](size_t n) { n = (n + 3) & ~(size_t)3; float* q = p + off; off += n; return q; };
    float* nf   = alloc((size_t)NN * DD);
    float* hid  = alloc((size_t)NN * DD);
    float* btp  = alloc((size_t)NN * DD);
    float* agg  = alloc((size_t)NN * DD);
    float* cnt  = alloc(NN);
    unsigned short* ehs = (unsigned short*)alloc((size_t)(NE + 16) * EH_ / 2);  // bf16
    float* WihT = alloc(192 * 64);
    float* WhhT = alloc(192 * 64);
    float* WlT  = alloc(64 * 64);
    int* hist   = (int*)alloc(NN);
    int* rowptr = (int*)alloc(NN + 1);
    int* cursor = (int*)alloc(NN);
    int* perm   = (int*)alloc(NE);
    int* dsts_s = (int*)alloc(NE);
    int* g_src  = (int*)alloc(GCAP);
    int* g_base = (int*)alloc(GCAP);
    int* g_cnt  = (int*)alloc(GCAP);
    int* d_ng   = (int*)alloc(4);
    unsigned short* Apk = (unsigned short*)alloc((size_t)(1 << 19) / 2);       // bf16, 1MB
    unsigned short* xpb = (unsigned short*)alloc((size_t)PADN * DD / 2);       // bf16

    // ---- one-time preprocessing ----
    k_zero<<<(NN + 255) / 256, 256, 0, stream>>>(cnt, NN);
    k_zero<<<(NN + 255) / 256, 256, 0, stream>>>((float*)hist, NN);
    k_zero<<<(GCAP + 255) / 256, 256, 0, stream>>>((float*)g_src, GCAP);
    k_zero<<<(GCAP + 255) / 256, 256, 0, stream>>>((float*)g_base, GCAP);
    k_zero<<<(GCAP + 255) / 256, 256, 0, stream>>>((float*)g_cnt, GCAP);
    k_proj<<<(NN + 3) / 4, 256, 0, stream>>>(x, Wp, bp, nf, hid);
    k_pA<<<(1 << 19) / 256, 256, 0, stream>>>(W2, Apk);
    k_tG<<<48, 256, 0, stream>>>(Wih, WihT);
    k_tG<<<48, 256, 0, stream>>>(Whh, WhhT);
    k_tr64<<<16, 256, 0, stream>>>(Wl, WlT);
    k_cnt<<<(NE + 255) / 256, 256, 0, stream>>>(dstv, cnt);
    k_hist<<<(NE + 255) / 256, 256, 0, stream>>>(srcv, hist);
    k_scan<<<1, 1024, 0, stream>>>(hist, rowptr, cursor);
    k_scatter<<<(NE + 255) / 256, 256, 0, stream>>>(srcv, dstv, cursor, perm, dsts_s);
    k_eh_s<<<(NE + 1) / 2, 256, 0, stream>>>(ea, W1, b1, perm, ehs);
    k_grp<<<1, 1024, 0, stream>>>(rowptr, g_src, g_base, g_cnt, d_ng);

    const int nw_quarter = (NN + 3) / 4;
    k_xp<<<(nw_quarter + 3) / 4, 256, 0, stream>>>(nf, WlT, bl, b2, xpb, btp, agg);
    for (int s = 0; s < NSTEPS; s++) {
        k_fv<<<GCAP / 16, 1024, 0, stream>>>(xpb, Apk, g_src, g_base, g_cnt, d_ng,
                                             ehs, dsts_s, btp, agg);
        float* dest = (s == NSTEPS - 1) ? (float*)d_out : nf;
        k_gruxp<<<(nw_quarter + 3) / 4, 256, 0, stream>>>(agg, cnt, hid, WihT, WhhT,
                                                          bih, bhh, WlT, bl, b2,
                                                          dest, xpb, btp, agg,
                                                          (s < NSTEPS - 1) ? 1 : 0);
    }
}